// Round 9
// baseline (588.458 us; speedup 1.0000x reference)
//
#include <hip/hip_runtime.h>
#include <math.h>

#define Bb_ 32
#define Nn_ 512
#define Ff_ 32
#define Tt_ 24
#define GC_ 64
#define TC_ 64
#define HS_ 12582912

typedef __attribute__((ext_vector_type(8))) short bf16x8;
typedef __attribute__((ext_vector_type(4))) float f32x4;
typedef __attribute__((ext_vector_type(8))) unsigned short u16x8;
typedef __attribute__((ext_vector_type(4))) unsigned short u16x4;

__device__ __forceinline__ float sigmoidf_(float v) { return 1.0f / (1.0f + __expf(-v)); }

__device__ __forceinline__ unsigned short f2bf(float f) {
    unsigned u = __float_as_uint(f);
    u = (u + 0x7fffu + ((u >> 16) & 1u)) >> 16;
    return (unsigned short)u;
}
__device__ __forceinline__ float bf2f(unsigned short h) {
    return __uint_as_float(((unsigned)h) << 16);
}

__device__ __forceinline__ void async16(const void* g, void* l) {
    __builtin_amdgcn_global_load_lds((const __attribute__((address_space(1))) unsigned int*)g,
                                     (__attribute__((address_space(3))) unsigned int*)l,
                                     16, 0, 0);
}

// fused ka_tmp + kb_rhs: one pass over x, 8-row groups.
// tmp[b,t,f] += w1[n]*x[b,n,f,t] (atomic, tmp pre-zeroed by kprep)
// rhs_t[b,n,t] = sum_f w3[f]*x[b,n,f,t]
__global__ __launch_bounds__(256) void kab(const float* __restrict__ x,
                                           const float* __restrict__ w1,
                                           const float* __restrict__ w3,
                                           float* __restrict__ tmp,
                                           float* __restrict__ rhs_t) {
    __shared__ float xr[8][768];
    __shared__ float w3S[32];
    int b = blockIdx.y, n0 = blockIdx.x * 32, tid = threadIdx.x;
    if (tid < 32) w3S[tid] = w3[tid];
    float a0 = 0.f, a1 = 0.f, a2 = 0.f;
    for (int g = 0; g < 4; ++g) {
#pragma unroll
        for (int r = 0; r < 8; ++r) {
            int n = n0 + g * 8 + r;
            const float* xp = x + ((size_t)(b * Nn_ + n)) * 768;
            float v0 = xp[tid], v1 = xp[tid + 256], v2 = xp[tid + 512];
            float w = w1[n];
            a0 += w * v0;
            a1 += w * v1;
            a2 += w * v2;
            xr[r][tid] = v0;
            xr[r][tid + 256] = v1;
            xr[r][tid + 512] = v2;
        }
        __syncthreads();
        if (tid < 192) {
            int r = tid / 24, t = tid - r * 24;
            int n = n0 + g * 8 + r;
            float s = 0.f;
#pragma unroll
            for (int f = 0; f < 32; ++f) s += w3S[f] * xr[r][f * 24 + t];
            rhs_t[(b * Nn_ + n) * Tt_ + t] = s;
        }
        __syncthreads();
    }
    // acc index i corresponds to x offset i = f*24+t; tmp layout [b][t*32+f]
    {
        int i = tid;
        int f = i / 24, t = i - f * 24;
        atomicAdd(tmp + b * 768 + t * 32 + f, a0);
        i = tid + 256;
        f = i / 24; t = i - f * 24;
        atomicAdd(tmp + b * 768 + t * 32 + f, a1);
        i = tid + 512;
        f = i / 24; t = i - f * 24;
        atomicAdd(tmp + b * 768 + t * 32 + f, a2);
    }
}

__global__ void kc_lhs(const float* __restrict__ tmp, const float* __restrict__ w2,
                       float* __restrict__ lhs_t) {
    int tid = blockIdx.x * blockDim.x + threadIdx.x;
    int n = tid % Nn_;
    int t = (tid / Nn_) % Tt_;
    int b = tid / (Nn_ * Tt_);
    const float* tp = tmp + (b * Tt_ + t) * Ff_;
    float s = 0.f;
#pragma unroll
    for (int f = 0; f < Ff_; ++f) s += tp[f] * w2[f * Nn_ + n];
    lhs_t[(b * Tt_ + t) * Nn_ + n] = s;
}

__global__ __launch_bounds__(576) void kd_temporal(const float* __restrict__ lhs_t,
                                                   const float* __restrict__ rhs_t,
                                                   const float* __restrict__ ta_bias,
                                                   const float* __restrict__ ta_proj,
                                                   float* __restrict__ temp_w) {
    __shared__ float rl[Nn_ * Tt_];
    __shared__ float sg[Tt_ * Tt_];
    __shared__ float Eb[Tt_ * Tt_];
    int b = blockIdx.x;
    int tid = threadIdx.x;
    for (int i = tid; i < Nn_ * Tt_; i += 576) rl[i] = rhs_t[b * Nn_ * Tt_ + i];
    __syncthreads();
    int u = tid % Tt_;
    int t = tid / Tt_;
    const float* lp = lhs_t + (b * Tt_ + t) * Nn_;
    float s = 0.f;
    for (int n = 0; n < Nn_; ++n) s += lp[n] * rl[n * Tt_ + u];
    sg[t * Tt_ + u] = sigmoidf_(s + ta_bias[t * Tt_ + u]);
    __syncthreads();
    float e = 0.f;
#pragma unroll
    for (int k = 0; k < Tt_; ++k) e += ta_proj[t * Tt_ + k] * sg[k * Tt_ + u];
    Eb[t * Tt_ + u] = e;
    __syncthreads();
    if (tid < Tt_) {
        int uu = tid;
        float m = -1e30f;
        for (int s2 = 0; s2 < Tt_; ++s2) m = fmaxf(m, Eb[s2 * Tt_ + uu]);
        float sum = 0.f;
        for (int s2 = 0; s2 < Tt_; ++s2) sum += __expf(Eb[s2 * Tt_ + uu] - m);
        float inv = 1.0f / sum;
        for (int s2 = 0; s2 < Tt_; ++s2)
            temp_w[b * Tt_ * Tt_ + s2 * Tt_ + uu] = __expf(Eb[s2 * Tt_ + uu] - m) * inv;
    }
}

__global__ __launch_bounds__(256) void ke_spatial(const float* __restrict__ x,
                                                  const float* __restrict__ tw,
                                                  const float* __restrict__ sa_wa,
                                                  const float* __restrict__ sa_wb,
                                                  const float* __restrict__ sa_wc,
                                                  float* __restrict__ lhs_s,
                                                  float* __restrict__ rhs_s) {
    __shared__ float xl[Ff_ * Tt_];
    __shared__ float twl[Tt_ * Tt_];
    __shared__ float xtl[Ff_ * Tt_];
    __shared__ float tmp2[Ff_];
    int n = blockIdx.x, b = blockIdx.y, tid = threadIdx.x;
    const float* xp = x + ((size_t)(b * Nn_ + n)) * Ff_ * Tt_;
    for (int i = tid; i < Ff_ * Tt_; i += 256) xl[i] = xp[i];
    for (int i = tid; i < Tt_ * Tt_; i += 256) twl[i] = tw[b * Tt_ * Tt_ + i];
    __syncthreads();
    for (int i = tid; i < Ff_ * Tt_; i += 256) {
        int f = i / Tt_, u = i % Tt_;
        float s = 0.f;
#pragma unroll
        for (int t = 0; t < Tt_; ++t) s += xl[f * Tt_ + t] * twl[t * Tt_ + u];
        xtl[i] = s;
    }
    __syncthreads();
    if (tid < Ff_) {
        float s = 0.f;
#pragma unroll
        for (int t = 0; t < Tt_; ++t) s += xtl[tid * Tt_ + t] * sa_wa[t];
        tmp2[tid] = s;
    }
    __syncthreads();
    if (tid < Tt_) {
        float a = 0.f, r = 0.f;
#pragma unroll
        for (int f = 0; f < Ff_; ++f) {
            a += tmp2[f] * sa_wb[f * Tt_ + tid];
            r += sa_wc[f] * xtl[f * Tt_ + tid];
        }
        int o = (b * Nn_ + n) * Tt_ + tid;
        lhs_s[o] = a;
        rhs_s[o] = r;
    }
}

// attnT[b][p][m] = sigmoid(lhs_s[m].rhs_s[p] + sa_bias[m][p]) split into bf16 hi/lo
__global__ __launch_bounds__(256) void kg_attnT(const float* __restrict__ lhs_s,
                                                const float* __restrict__ rhs_s,
                                                const float* __restrict__ sa_bias,
                                                unsigned short* __restrict__ aTh,
                                                unsigned short* __restrict__ aTl) {
    __shared__ float L[256 * 25];
    __shared__ float R[16 * Tt_];
    __shared__ float Bt[256 * 17];
    int b = blockIdx.y, tid = threadIdx.x;
    int p0 = (blockIdx.x >> 1) * 16;
    int m0 = (blockIdx.x & 1) * 256;
    for (int i = tid; i < 256 * Tt_; i += 256) {
        int m = i / Tt_, t = i - m * Tt_;
        L[m * 25 + t] = lhs_s[b * Nn_ * Tt_ + (m0 + m) * Tt_ + t];
    }
    for (int i = tid; i < 16 * Tt_; i += 256) R[i] = rhs_s[b * Nn_ * Tt_ + p0 * Tt_ + i];
    for (int i = tid; i < 256 * 16; i += 256) {
        int m = i >> 4, j = i & 15;
        Bt[m * 17 + j] = sa_bias[(size_t)(m0 + m) * Nn_ + p0 + j];
    }
    __syncthreads();
    for (int idx = tid; idx < 16 * 256; idx += 256) {
        int r = idx >> 8, mm = idx & 255;
        const float* lp = L + mm * 25;
        const float* rp = R + r * Tt_;
        float s = 0.f;
#pragma unroll
        for (int t = 0; t < Tt_; ++t) s += lp[t] * rp[t];
        float v = sigmoidf_(s + Bt[mm * 17 + r]);
        unsigned short hi = f2bf(v);
        size_t o = ((size_t)b * Nn_ + p0 + r) * Nn_ + m0 + mm;
        aTh[o] = hi;
        aTl[o] = f2bf(v - bf2f(hi));
    }
}

__global__ void kprojsplit(const float* __restrict__ proj,
                           unsigned short* __restrict__ pBh,
                           unsigned short* __restrict__ pBl) {
    int i = blockIdx.x * 256 + threadIdx.x;
    float v = proj[i];
    unsigned short hi = f2bf(v);
    pBh[i] = hi;
    pBl[i] = f2bf(v - bf2f(hi));
}

// chebT[k][p][m] = cheb[k][m][p]
__global__ __launch_bounds__(256) void kchebT(const float* __restrict__ cheb,
                                              float* __restrict__ chebT) {
    __shared__ float tl[64][65];
    int p0 = blockIdx.x * 64, m0 = blockIdx.y * 64, k = blockIdx.z;
    int tid = threadIdx.x, j = tid & 63, i4 = tid >> 6;
#pragma unroll
    for (int r = 0; r < 16; ++r) {
        int i = i4 + r * 4;
        tl[i][j] = cheb[(size_t)k * Nn_ * Nn_ + (size_t)(m0 + i) * Nn_ + p0 + j];
    }
    __syncthreads();
#pragma unroll
    for (int r = 0; r < 16; ++r) {
        int pp = i4 + r * 4;
        chebT[(size_t)k * Nn_ * Nn_ + (size_t)(p0 + pp) * Nn_ + m0 + j] = tl[j][pp];
    }
}

// ST[b][p][n] = sum_m attnT[b][p][m] * proj[n][m]  via split-bf16 MFMA
// XCD-swizzled: 512 blocks = 8 XCDs x 64; blocks sharing a b (A-panel) co-locate.
__global__ __launch_bounds__(256) void ksgemm_mfma(const unsigned short* __restrict__ aTh,
                                                   const unsigned short* __restrict__ aTl,
                                                   const unsigned short* __restrict__ pBh,
                                                   const unsigned short* __restrict__ pBl,
                                                   float* __restrict__ ST) {
    __shared__ unsigned short Ah[512 * 8], Al[512 * 8], Bh[512 * 8], Bl[512 * 8];
    int lin = blockIdx.x + 4 * (blockIdx.y + 4 * blockIdx.z);   // 0..511
    lin = (lin & 7) * 64 + (lin >> 3);                          // bijective (512%8==0)
    int nt = lin & 3;
    int pt = (lin >> 2) & 3;
    int b = lin >> 4;
    int p0 = pt * 128, n0 = nt * 128;
    int tid = threadIdx.x, wid = tid >> 6, lane = tid & 63;
    int l15 = lane & 15, l4 = lane >> 4;
    int wm = (wid & 1) * 64, wn = (wid >> 1) * 64;
    const unsigned short* Abh = aTh + (size_t)b * Nn_ * Nn_;
    const unsigned short* Abl = aTl + (size_t)b * Nn_ * Nn_;

    int cp0 = wid * 128 + lane, cp1 = cp0 + 64;
    int r0 = cp0 >> 2, k0c = (cp0 & 3) ^ ((r0 >> 1) & 3);
    int r1 = cp1 >> 2, k1c = (cp1 & 3) ^ ((r1 >> 1) & 3);
    const unsigned short* gAh0 = Abh + (size_t)(p0 + r0) * Nn_ + k0c * 8;
    const unsigned short* gAh1 = Abh + (size_t)(p0 + r1) * Nn_ + k1c * 8;
    const unsigned short* gAl0 = Abl + (size_t)(p0 + r0) * Nn_ + k0c * 8;
    const unsigned short* gAl1 = Abl + (size_t)(p0 + r1) * Nn_ + k1c * 8;
    const unsigned short* gBh0 = pBh + (size_t)(n0 + r0) * Nn_ + k0c * 8;
    const unsigned short* gBh1 = pBh + (size_t)(n0 + r1) * Nn_ + k1c * 8;
    const unsigned short* gBl0 = pBl + (size_t)(n0 + r0) * Nn_ + k0c * 8;
    const unsigned short* gBl1 = pBl + (size_t)(n0 + r1) * Nn_ + k1c * 8;
    unsigned short* lAh0 = Ah + (size_t)cp0 * 8;
    unsigned short* lAh1 = Ah + (size_t)cp1 * 8;
    unsigned short* lAl0 = Al + (size_t)cp0 * 8;
    unsigned short* lAl1 = Al + (size_t)cp1 * 8;
    unsigned short* lBh0 = Bh + (size_t)cp0 * 8;
    unsigned short* lBh1 = Bh + (size_t)cp1 * 8;
    unsigned short* lBl0 = Bl + (size_t)cp0 * 8;
    unsigned short* lBl1 = Bl + (size_t)cp1 * 8;

    int ca[4], cb[4];
#pragma unroll
    for (int i = 0; i < 4; ++i) {
        int row = wm + i * 16 + l15;
        ca[i] = row * 4 + (l4 ^ ((row >> 1) & 3));
        row = wn + i * 16 + l15;
        cb[i] = row * 4 + (l4 ^ ((row >> 1) & 3));
    }

    f32x4 acc[4][4];
#pragma unroll
    for (int i = 0; i < 4; ++i)
#pragma unroll
        for (int j = 0; j < 4; ++j) acc[i][j] = (f32x4){0.f, 0.f, 0.f, 0.f};

    for (int ks = 0; ks < 16; ++ks) {
        __syncthreads();
        async16(gAh0 + ks * 32, lAh0);
        async16(gAh1 + ks * 32, lAh1);
        async16(gAl0 + ks * 32, lAl0);
        async16(gAl1 + ks * 32, lAl1);
        async16(gBh0 + ks * 32, lBh0);
        async16(gBh1 + ks * 32, lBh1);
        async16(gBl0 + ks * 32, lBl0);
        async16(gBl1 + ks * 32, lBl1);
        __syncthreads();
        bf16x8 ah[4], al[4], bh[4], bl[4];
#pragma unroll
        for (int i = 0; i < 4; ++i) {
            ah[i] = *(const bf16x8*)(Ah + (size_t)ca[i] * 8);
            al[i] = *(const bf16x8*)(Al + (size_t)ca[i] * 8);
        }
#pragma unroll
        for (int j = 0; j < 4; ++j) {
            bh[j] = *(const bf16x8*)(Bh + (size_t)cb[j] * 8);
            bl[j] = *(const bf16x8*)(Bl + (size_t)cb[j] * 8);
        }
#pragma unroll
        for (int i = 0; i < 4; ++i)
#pragma unroll
            for (int j = 0; j < 4; ++j) {
                acc[i][j] = __builtin_amdgcn_mfma_f32_16x16x32_bf16(ah[i], bh[j], acc[i][j], 0, 0, 0);
                acc[i][j] = __builtin_amdgcn_mfma_f32_16x16x32_bf16(ah[i], bl[j], acc[i][j], 0, 0, 0);
                acc[i][j] = __builtin_amdgcn_mfma_f32_16x16x32_bf16(al[i], bh[j], acc[i][j], 0, 0, 0);
            }
    }

    float* Cb = ST + (size_t)b * Nn_ * Nn_;
#pragma unroll
    for (int i = 0; i < 4; ++i)
#pragma unroll
        for (int j = 0; j < 4; ++j) {
            int p = p0 + wm + i * 16 + l4 * 4;
            int n = n0 + wn + j * 16 + l15;
#pragma unroll
            for (int r = 0; r < 4; ++r)
                Cb[(size_t)(p + r) * Nn_ + n] = acc[i][j][r];
        }
}

// fused row-softmax + cheb multiply + bf16 AT write (one wave per ST row)
__global__ __launch_bounds__(256) void kjaT(const float* __restrict__ ST,
                                            const float* __restrict__ chebT,
                                            unsigned short* __restrict__ AT) {
    int row = blockIdx.x * 4 + (threadIdx.x >> 6);   // b*512 + p
    int lane = threadIdx.x & 63;
    const float* rp = ST + (size_t)row * Nn_ + lane * 8;
    float4 a = *(const float4*)rp;
    float4 c = *(const float4*)(rp + 4);
    float m = fmaxf(fmaxf(fmaxf(a.x, a.y), fmaxf(a.z, a.w)),
                    fmaxf(fmaxf(c.x, c.y), fmaxf(c.z, c.w)));
#pragma unroll
    for (int off = 32; off > 0; off >>= 1) m = fmaxf(m, __shfl_xor(m, off, 64));
    float e[8];
    e[0] = __expf(a.x - m); e[1] = __expf(a.y - m); e[2] = __expf(a.z - m); e[3] = __expf(a.w - m);
    e[4] = __expf(c.x - m); e[5] = __expf(c.y - m); e[6] = __expf(c.z - m); e[7] = __expf(c.w - m);
    float s = e[0] + e[1] + e[2] + e[3] + e[4] + e[5] + e[6] + e[7];
#pragma unroll
    for (int off = 32; off > 0; off >>= 1) s += __shfl_xor(s, off, 64);
    float inv = 1.0f / s;
#pragma unroll
    for (int i = 0; i < 8; ++i) e[i] *= inv;
    int b = row >> 9, p = row & 511;
#pragma unroll
    for (int k = 0; k < 3; ++k) {
        const float* cp = chebT + (size_t)k * 262144 + (size_t)p * Nn_ + lane * 8;
        float4 c0 = *(const float4*)cp;
        float4 c1 = *(const float4*)(cp + 4);
        u16x4 o0, o1;
        o0[0] = f2bf(c0.x * e[0]); o0[1] = f2bf(c0.y * e[1]);
        o0[2] = f2bf(c0.z * e[2]); o0[3] = f2bf(c0.w * e[3]);
        o1[0] = f2bf(c1.x * e[4]); o1[1] = f2bf(c1.y * e[5]);
        o1[2] = f2bf(c1.z * e[6]); o1[3] = f2bf(c1.w * e[7]);
        unsigned short* op = AT + (size_t)k * 8388608 + (size_t)b * 262144 + (size_t)p * Nn_ + lane * 8;
        *(u16x4*)op = o0;
        *(u16x4*)(op + 4) = o1;
    }
}

// XT[b][q][m] bf16 = x[b][m][q]
__global__ __launch_bounds__(256) void kxT(const float* __restrict__ x,
                                           unsigned short* __restrict__ XT) {
    __shared__ float tl[64][65];
    int q0 = blockIdx.x * 64, m0 = blockIdx.y * 64, b = blockIdx.z;
    int tid = threadIdx.x, j = tid & 63, i4 = tid >> 6;
#pragma unroll
    for (int r = 0; r < 16; ++r) {
        int i = i4 + r * 4;
        tl[i][j] = x[((size_t)(b * Nn_ + m0 + i)) * 768 + q0 + j];
    }
    __syncthreads();
#pragma unroll
    for (int r = 0; r < 16; ++r) {
        int qq = i4 + r * 4;
        XT[((size_t)b * 768 + q0 + qq) * Nn_ + m0 + j] = f2bf(tl[j][qq]);
    }
}

// H[b][p][q] bf16 = sum_m AT_k[b][p][m] * XT[b][q][m]; grid.z = k*32+b (3 k fused)
// XCD-swizzled: 2304 blocks = 8 XCDs x 288 = 12 whole z-slices per XCD.
// One z-slice's A-panel (524KB) + B-panel (786KB) = 1.3MB fits one XCD L2.
__global__ __launch_bounds__(256) void hgemm_mfma(const unsigned short* __restrict__ AT,
                                                  const unsigned short* __restrict__ XT,
                                                  unsigned short* __restrict__ H) {
    __shared__ unsigned short As[512 * 8];
    __shared__ unsigned short Bs[512 * 8];
    int lin = blockIdx.x + 6 * (blockIdx.y + 4 * blockIdx.z);   // 0..2303
    lin = (lin & 7) * 288 + (lin >> 3);                         // bijective (2304%8==0)
    int qt = lin % 6;
    int rem = lin / 6;
    int pt = rem & 3;
    int bz = rem >> 2;
    int b = bz & 31, kk2 = bz >> 5;
    int p0 = pt * 128;
    int q0 = qt * 128;
    int tid = threadIdx.x;
    int wid = tid >> 6, lane = tid & 63;
    int l15 = lane & 15, l4 = lane >> 4;
    int wm = (wid & 1) * 64, wn = (wid >> 1) * 64;
    const unsigned short* Ab = AT + (size_t)kk2 * 8388608 + (size_t)b * Nn_ * Nn_;
    const unsigned short* Bb = XT + (size_t)b * 768 * Nn_;

    int cp0 = wid * 128 + lane;
    int cp1 = cp0 + 64;
    int rA0 = cp0 >> 2, kA0 = (cp0 & 3) ^ ((rA0 >> 1) & 3);
    int rA1 = cp1 >> 2, kA1 = (cp1 & 3) ^ ((rA1 >> 1) & 3);
    const unsigned short* gA0 = Ab + (size_t)(p0 + rA0) * Nn_ + kA0 * 8;
    const unsigned short* gA1 = Ab + (size_t)(p0 + rA1) * Nn_ + kA1 * 8;
    const unsigned short* gB0 = Bb + (size_t)(q0 + rA0) * Nn_ + kA0 * 8;
    const unsigned short* gB1 = Bb + (size_t)(q0 + rA1) * Nn_ + kA1 * 8;
    unsigned short* lA0 = As + (size_t)(wid * 128) * 8;
    unsigned short* lA1 = As + (size_t)(wid * 128 + 64) * 8;
    unsigned short* lB0 = Bs + (size_t)(wid * 128) * 8;
    unsigned short* lB1 = Bs + (size_t)(wid * 128 + 64) * 8;

    int ca[4], cb[4];
#pragma unroll
    for (int i = 0; i < 4; ++i) {
        int row = wm + i * 16 + l15;
        ca[i] = row * 4 + (l4 ^ ((row >> 1) & 3));
        row = wn + i * 16 + l15;
        cb[i] = row * 4 + (l4 ^ ((row >> 1) & 3));
    }

    f32x4 acc[4][4];
#pragma unroll
    for (int i = 0; i < 4; ++i)
#pragma unroll
        for (int j = 0; j < 4; ++j) acc[i][j] = (f32x4){0.f, 0.f, 0.f, 0.f};

    for (int ks = 0; ks < 16; ++ks) {
        __syncthreads();
        async16(gA0 + ks * 32, lA0);
        async16(gA1 + ks * 32, lA1);
        async16(gB0 + ks * 32, lB0);
        async16(gB1 + ks * 32, lB1);
        __syncthreads();
        bf16x8 af[4], bfv[4];
#pragma unroll
        for (int i = 0; i < 4; ++i) af[i] = *(const bf16x8*)(As + (size_t)ca[i] * 8);
#pragma unroll
        for (int j = 0; j < 4; ++j) bfv[j] = *(const bf16x8*)(Bs + (size_t)cb[j] * 8);
#pragma unroll
        for (int i = 0; i < 4; ++i)
#pragma unroll
            for (int j = 0; j < 4; ++j)
                acc[i][j] = __builtin_amdgcn_mfma_f32_16x16x32_bf16(af[i], bfv[j], acc[i][j], 0, 0, 0);
    }

    unsigned short* Hb = H + (size_t)kk2 * HS_ + (size_t)b * Nn_ * 768;
#pragma unroll
    for (int i = 0; i < 4; ++i)
#pragma unroll
        for (int j = 0; j < 4; ++j) {
            int p = p0 + wm + i * 16 + l4 * 4;
            int q = q0 + wn + j * 16 + l15;
#pragma unroll
            for (int r = 0; r < 4; ++r)
                Hb[(size_t)(p + r) * 768 + q] = f2bf(acc[i][j][r]);
        }
}

// prep: WA[r][kf] bf16 (kf<96: w_cheb[kf][r]; kf>=96: skip_w[r][kf-96])
//       WC[(j*64+c)][g] bf16 = time_w[c][g][j]; also zero tmp for kab atomics
__global__ void kprep(const float* __restrict__ wch, const float* __restrict__ skw,
                      const float* __restrict__ tw,
                      unsigned short* __restrict__ WA, unsigned short* __restrict__ WC,
                      float* __restrict__ tmp) {
    int tid = threadIdx.x;
    for (int i = tid; i < 64 * 128; i += 256) {
        int r = i >> 7, kf = i & 127;
        float v = (kf < 96) ? wch[kf * 64 + r] : skw[r * 32 + (kf - 96)];
        WA[i] = f2bf(v);
    }
    for (int i = tid; i < 192 * 64; i += 256) {
        int j = i / 4096, c = (i >> 6) & 63, g = i & 63;
        WC[i] = f2bf(tw[c * 192 + g * 3 + j]);
    }
    for (int i = tid; i < 24576; i += 256) tmp[i] = 0.f;
}

// -------- fused tail, 4-tile persistent blocks: each block processes 4
// consecutive (b, 4n) tiles. Weight frags loaded once; tile i+1's H/x data
// loaded to REGISTERS during tile i's compute (T14 split; barriers drain
// vmcnt so cover = stage2), written to Hl after the stage1 barrier.
// Grid 32x32 = 1024 blocks = exactly 4/CU co-resident, one round.
// lnP scratch clobbers Gl row 0 (border) -> re-zeroed per tile. --
__global__ __launch_bounds__(256, 4) void ktail(const unsigned short* __restrict__ H,
                                                const float* __restrict__ x,
                                                const unsigned short* __restrict__ WA,
                                                const unsigned short* __restrict__ WC,
                                                const float* __restrict__ time_b,
                                                const float* __restrict__ skip_b,
                                                const float* __restrict__ ln_g,
                                                const float* __restrict__ ln_b,
                                                float* __restrict__ out) {
    __shared__ __align__(16) unsigned short Hl[96 * 16 * 8];   // 96 cols x 16 chunks x 8 shorts
    __shared__ __align__(16) unsigned short Gl[104 * 64];      // 104 rows x 8 chunks x 8 shorts
    __shared__ float biasS[64], lgS[64], lbS[64];
    __shared__ float muS[96], rsS[96];

    int b = blockIdx.y;
    int nb = blockIdx.x * 16;          // 4 tiles: n0 = nb + tc*4
    int tid = threadIdx.x;
    int w = tid >> 6, lane = tid & 63, l15 = lane & 15, l4 = lane >> 4;

    // weight fragments (once per block, amortized over 4 tiles)
    bf16x8 af[4], cf[3][2];
#pragma unroll
    for (int q = 0; q < 4; ++q)
        af[q] = *(const bf16x8*)(WA + (size_t)(16 * w + l15) * 128 + q * 32 + l4 * 8);
#pragma unroll
    for (int j = 0; j < 3; ++j)
#pragma unroll
        for (int kc = 0; kc < 2; ++kc)
            cf[j][kc] = *(const bf16x8*)(WC + (size_t)(j * 64 + 16 * w + l15) * 64 + kc * 32 + l4 * 8);

    // per-thread staging-unit decode (tile-invariant): unit u=(((k*8+fg)*4+n)*6+tg)
    int utg[3], un[3], ufg[3], uk[3];
#pragma unroll
    for (int i = 0; i < 3; ++i) {
        int u = i * 256 + tid;
        utg[i] = u % 6;
        int r1 = u / 6;
        un[i] = r1 & 3;
        int r2 = r1 >> 2;
        ufg[i] = r2 & 7;
        uk[i] = r2 >> 3;
    }

    u16x4 rg[3][4];   // staging registers (one tile in flight)

    auto regload = [&](int n0) {
#pragma unroll
        for (int i = 0; i < 3; ++i) {
            int t0 = utg[i] * 4, f0 = ufg[i] * 4;
            if (uk[i] < 3) {
                const unsigned short* hp = H + (size_t)uk[i] * HS_ +
                                           ((size_t)b * Nn_ + n0 + un[i]) * 768 + f0 * 24 + t0;
                rg[i][0] = *(const u16x4*)hp;
                rg[i][1] = *(const u16x4*)(hp + 24);
                rg[i][2] = *(const u16x4*)(hp + 48);
                rg[i][3] = *(const u16x4*)(hp + 72);
            } else {
                const float* xp = x + ((size_t)b * Nn_ + n0 + un[i]) * 768 + f0 * 24 + t0;
                float4 v0 = *(const float4*)xp;
                float4 v1 = *(const float4*)(xp + 24);
                float4 v2 = *(const float4*)(xp + 48);
                float4 v3 = *(const float4*)(xp + 72);
                rg[i][0] = (u16x4){f2bf(v0.x), f2bf(v0.y), f2bf(v0.z), f2bf(v0.w)};
                rg[i][1] = (u16x4){f2bf(v1.x), f2bf(v1.y), f2bf(v1.z), f2bf(v1.w)};
                rg[i][2] = (u16x4){f2bf(v2.x), f2bf(v2.y), f2bf(v2.z), f2bf(v2.w)};
                rg[i][3] = (u16x4){f2bf(v3.x), f2bf(v3.y), f2bf(v3.z), f2bf(v3.w)};
            }
        }
    };
    auto hlwrite = [&]() {
#pragma unroll
        for (int i = 0; i < 3; ++i) {
            int t0 = utg[i] * 4;
            int kc4 = uk[i] * 4 + (ufg[i] >> 1);
            int half = ufg[i] & 1;
#pragma unroll
            for (int s = 0; s < 4; ++s) {
                int col = un[i] * 24 + t0 + s;
                int pos = col * 16 + (kc4 ^ ((col ^ (col >> 2)) & 7));
                u16x4 o = (u16x4){rg[i][0][s], rg[i][1][s], rg[i][2][s], rg[i][3][s]};
                *(u16x4*)(Hl + pos * 8 + half * 4) = o;
            }
        }
    };

    // prologue: tile 0 staged; borders + params
    regload(nb);
    if (tid < 64) {
        int n = tid >> 4, rr = (tid >> 3) & 1, gc = tid & 7;
        int row = n * 26 + rr * 25;
        int posg = row * 8 + (gc ^ (row & 7));
        *(float4*)(void*)(Gl + posg * 8) = make_float4(0.f, 0.f, 0.f, 0.f);
        biasS[tid] = time_b[tid] + skip_b[tid];
        lgS[tid] = ln_g[tid];
        lbS[tid] = ln_b[tid];
    }
    hlwrite();
    __syncthreads();
    regload(nb + 4);   // tile 1 in flight during tile 0 stage1

#pragma unroll
    for (int tc = 0; tc < 4; ++tc) {
        int n0 = nb + tc * 4;

        // stage 1: gcn (K=96) + skip (K=32), relu(gcn) -> Gl bf16
        f32x4 accs[6];
#pragma unroll
        for (int ct = 0; ct < 6; ++ct) {
            int col = ct * 16 + l15;
            int cx = (col ^ (col >> 2)) & 7;
            bf16x8 h0 = *(const bf16x8*)(Hl + (col * 16 + ((0 + l4) ^ cx)) * 8);
            bf16x8 h1 = *(const bf16x8*)(Hl + (col * 16 + ((4 + l4) ^ cx)) * 8);
            bf16x8 h2 = *(const bf16x8*)(Hl + (col * 16 + ((8 + l4) ^ cx)) * 8);
            bf16x8 h3 = *(const bf16x8*)(Hl + (col * 16 + ((12 + l4) ^ cx)) * 8);
            f32x4 g = (f32x4){0.f, 0.f, 0.f, 0.f};
            g = __builtin_amdgcn_mfma_f32_16x16x32_bf16(af[0], h0, g, 0, 0, 0);
            g = __builtin_amdgcn_mfma_f32_16x16x32_bf16(af[1], h1, g, 0, 0, 0);
            g = __builtin_amdgcn_mfma_f32_16x16x32_bf16(af[2], h2, g, 0, 0, 0);
            f32x4 s = (f32x4){0.f, 0.f, 0.f, 0.f};
            s = __builtin_amdgcn_mfma_f32_16x16x32_bf16(af[3], h3, s, 0, 0, 0);
            accs[ct] = s;
            int n = col / 24, t = col - n * 24;
            int row = n * 26 + t + 1;
            int gc = 2 * w + (l4 >> 1);
            int posg = row * 8 + (gc ^ (row & 7));
            u16x4 pk;
#pragma unroll
            for (int r = 0; r < 4; ++r) pk[r] = f2bf(g[r] > 0.f ? g[r] : 0.f);
            *(u16x4*)(Gl + posg * 8 + (l4 & 1) * 4) = pk;
        }
        __syncthreads();   // B: Hl reads + Gl writes complete

        // write next tile's staged regs into Hl; refill regs with tile tc+2
        if (tc < 3) {
            hlwrite();
            if (tc < 2) regload(nb + (tc + 2) * 4);
        }

        // stage 2: conv as 3 shifted GEMMs (K=64) + skip + bias + relu -> regs
        f32x4 oo[6];
        float ps6[6], pq6[6];
#pragma unroll
        for (int ct = 0; ct < 6; ++ct) {
            int col = ct * 16 + l15;
            int n = col / 24, t = col - n * 24;
            f32x4 acc = accs[ct];
#pragma unroll
            for (int j = 0; j < 3; ++j) {
                int row = n * 26 + t + j;
                int rx = row & 7;
                bf16x8 g0 = *(const bf16x8*)(Gl + (row * 8 + (l4 ^ rx)) * 8);
                bf16x8 g1 = *(const bf16x8*)(Gl + (row * 8 + ((l4 + 4) ^ rx)) * 8);
                acc = __builtin_amdgcn_mfma_f32_16x16x32_bf16(cf[j][0], g0, acc, 0, 0, 0);
                acc = __builtin_amdgcn_mfma_f32_16x16x32_bf16(cf[j][1], g1, acc, 0, 0, 0);
            }
            int cb = 16 * w + 4 * l4;
            f32x4 bv = *(const f32x4*)(biasS + cb);
            f32x4 o;
#pragma unroll
            for (int r = 0; r < 4; ++r) {
                float v = acc[r] + bv[r];
                o[r] = v > 0.f ? v : 0.f;
            }
            oo[ct] = o;
            float ps = o[0] + o[1] + o[2] + o[3];
            float pq = o[0] * o[0] + o[1] * o[1] + o[2] * o[2] + o[3] * o[3];
            ps += __shfl_xor(ps, 16, 64);
            ps += __shfl_xor(ps, 32, 64);
            pq += __shfl_xor(pq, 16, 64);
            pq += __shfl_xor(pq, 32, 64);
            ps6[ct] = ps;
            pq6[ct] = pq;
        }
        __syncthreads();   // C: Gl reads done -> Gl rows 0..23 reusable as LN scratch

        float* lnP = (float*)Gl;   // [0..383] sums, [384..767] sq-sums (w*96+col)
        if (l4 == 0) {
#pragma unroll
            for (int ct = 0; ct < 6; ++ct) {
                int col = ct * 16 + l15;
                lnP[w * 96 + col] = ps6[ct];
                lnP[384 + w * 96 + col] = pq6[ct];
            }
        }
        __syncthreads();   // D
        if (tid < 96) {
            float s = lnP[tid] + lnP[96 + tid] + lnP[192 + tid] + lnP[288 + tid];
            float q = lnP[384 + tid] + lnP[480 + tid] + lnP[576 + tid] + lnP[672 + tid];
            float mu = s * (1.0f / 64.0f);
            float var = q * (1.0f / 64.0f) - mu * mu;
            muS[tid] = mu;
            rsS[tid] = rsqrtf(var + 1e-5f);
        }
        __syncthreads();   // E

        // direct register store: out[((b*N+n)*64+c)*24+t], c = 16w+4*l4+r
        float* ob = out + ((size_t)b * Nn_ + n0) * (TC_ * Tt_);
        int cb = 16 * w + 4 * l4;
        f32x4 lgv = *(const f32x4*)(lgS + cb);
        f32x4 lbv = *(const f32x4*)(lbS + cb);
#pragma unroll
        for (int ct = 0; ct < 6; ++ct) {
            int col = ct * 16 + l15;
            int n = col / 24, t = col - n * 24;
            float mu = muS[col], rs = rsS[col];
            f32x4 o = oo[ct];
            float* op = ob + (size_t)(n * 64 + cb) * 24 + t;
#pragma unroll
            for (int r = 0; r < 4; ++r)
                op[r * 24] = (o[r] - mu) * rs * lgv[r] + lbv[r];
        }
        // re-zero Gl row 0 (border clobbered by lnP); next stage2 read is
        // protected by next iteration's barrier B
        if (tc < 3 && tid < 8)
            *(float4*)(void*)(Gl + tid * 8) = make_float4(0.f, 0.f, 0.f, 0.f);
    }
}

extern "C" void kernel_launch(void* const* d_in, const int* in_sizes, int n_in,
                              void* d_out, int out_size, void* d_ws, size_t ws_size,
                              hipStream_t stream) {
    const float* x       = (const float*)d_in[0];
    const float* cheb    = (const float*)d_in[1];
    const float* w_cheb  = (const float*)d_in[2];
    const float* sa_wa   = (const float*)d_in[3];
    const float* sa_wb   = (const float*)d_in[4];
    const float* sa_wc   = (const float*)d_in[5];
    const float* sa_bias = (const float*)d_in[6];
    const float* sa_proj = (const float*)d_in[7];
    const float* ta_w1   = (const float*)d_in[8];
    const float* ta_w2   = (const float*)d_in[9];
    const float* ta_w3   = (const float*)d_in[10];
    const float* ta_bias = (const float*)d_in[11];
    const float* ta_proj = (const float*)d_in[12];
    const float* time_w  = (const float*)d_in[13];
    const float* time_b  = (const float*)d_in[14];
    const float* skip_w  = (const float*)d_in[15];
    const float* skip_b  = (const float*)d_in[16];
    const float* ln_g    = (const float*)d_in[17];
    const float* ln_b    = (const float*)d_in[18];
    float* out = (float*)d_out;

    // ---- workspace layout (~195 MB) ----
    float* cur   = (float*)d_ws;
    float* tmp   = cur;            cur += 24576;
    float* lhs_t = cur;            cur += 393216;
    float* rhs_t = cur;            cur += 393216;
    float* tw    = cur;            cur += 18432;
    float* lhs_s = cur;            cur += 393216;
    float* rhs_s = cur;            cur += 393216;
    unsigned short* WAbuf = (unsigned short*)cur;            // 8192 us
    unsigned short* WCbuf = WAbuf + 8192;                    // 12288 us
    cur += 10240;
    unsigned short* pBh = (unsigned short*)cur;              // 262144 us
    unsigned short* pBl = pBh + 262144;                      // 262144 us
    cur += 262144;
    float* chebT = cur;            cur += 786432;
    unsigned short* regionA = (unsigned short*)cur;          // attnT hi/lo, then AT x3
    unsigned short* aTh = regionA;
    unsigned short* aTl = regionA + 8388608;
    unsigned short* ATb = regionA;
    cur += 12582912;
    float* STbuf = cur;            cur += 8388608;
    unsigned short* XT = (unsigned short*)cur;               // 12582912 us
    cur += 6291456;
    unsigned short* hbuf = (unsigned short*)cur;             // 37748736 us

    kprep<<<1, 256, 0, stream>>>(w_cheb, skip_w, time_w, WAbuf, WCbuf, tmp);
    kprojsplit<<<1024, 256, 0, stream>>>(sa_proj, pBh, pBl);
    kchebT<<<dim3(8, 8, 3), 256, 0, stream>>>(cheb, chebT);
    kxT<<<dim3(12, 8, 32), 256, 0, stream>>>(x, XT);
    kab<<<dim3(16, 32), 256, 0, stream>>>(x, ta_w1, ta_w3, tmp, rhs_t);
    kc_lhs<<<1536, 256, 0, stream>>>(tmp, ta_w2, lhs_t);
    kd_temporal<<<32, 576, 0, stream>>>(lhs_t, rhs_t, ta_bias, ta_proj, tw);
    ke_spatial<<<dim3(512, 32), 256, 0, stream>>>(x, tw, sa_wa, sa_wb, sa_wc, lhs_s, rhs_s);
    kg_attnT<<<dim3(64, 32), 256, 0, stream>>>(lhs_s, rhs_s, sa_bias, aTh, aTl);
    ksgemm_mfma<<<dim3(4, 4, 32), 256, 0, stream>>>(aTh, aTl, pBh, pBl, STbuf);
    kjaT<<<4096, 256, 0, stream>>>(STbuf, chebT, ATb);
    hgemm_mfma<<<dim3(6, 4, 96), 256, 0, stream>>>(ATb, XT, hbuf);
    ktail<<<dim3(32, 32), 256, 0, stream>>>(hbuf, x, WAbuf, WCbuf,
                                            time_b, skip_b, ln_g, ln_b, out);
}

// Round 10
// 565.301 us; speedup vs baseline: 1.0410x; 1.0410x over previous
//
#include <hip/hip_runtime.h>
#include <math.h>

#define Bb_ 32
#define Nn_ 512
#define Ff_ 32
#define Tt_ 24
#define GC_ 64
#define TC_ 64
#define HS_ 12582912

typedef __attribute__((ext_vector_type(8))) short bf16x8;
typedef __attribute__((ext_vector_type(4))) float f32x4;
typedef __attribute__((ext_vector_type(8))) unsigned short u16x8;
typedef __attribute__((ext_vector_type(4))) unsigned short u16x4;

__device__ __forceinline__ float sigmoidf_(float v) { return 1.0f / (1.0f + __expf(-v)); }

__device__ __forceinline__ unsigned short f2bf(float f) {
    unsigned u = __float_as_uint(f);
    u = (u + 0x7fffu + ((u >> 16) & 1u)) >> 16;
    return (unsigned short)u;
}
__device__ __forceinline__ float bf2f(unsigned short h) {
    return __uint_as_float(((unsigned)h) << 16);
}

__device__ __forceinline__ void async16(const void* g, void* l) {
    __builtin_amdgcn_global_load_lds((const __attribute__((address_space(1))) unsigned int*)g,
                                     (__attribute__((address_space(3))) unsigned int*)l,
                                     16, 0, 0);
}

// fused ka_tmp + kb_rhs: one pass over x, 8-row groups.
__global__ __launch_bounds__(256) void kab(const float* __restrict__ x,
                                           const float* __restrict__ w1,
                                           const float* __restrict__ w3,
                                           float* __restrict__ tmp,
                                           float* __restrict__ rhs_t) {
    __shared__ float xr[8][768];
    __shared__ float w3S[32];
    int b = blockIdx.y, n0 = blockIdx.x * 32, tid = threadIdx.x;
    if (tid < 32) w3S[tid] = w3[tid];
    float a0 = 0.f, a1 = 0.f, a2 = 0.f;
    for (int g = 0; g < 4; ++g) {
#pragma unroll
        for (int r = 0; r < 8; ++r) {
            int n = n0 + g * 8 + r;
            const float* xp = x + ((size_t)(b * Nn_ + n)) * 768;
            float v0 = xp[tid], v1 = xp[tid + 256], v2 = xp[tid + 512];
            float w = w1[n];
            a0 += w * v0;
            a1 += w * v1;
            a2 += w * v2;
            xr[r][tid] = v0;
            xr[r][tid + 256] = v1;
            xr[r][tid + 512] = v2;
        }
        __syncthreads();
        if (tid < 192) {
            int r = tid / 24, t = tid - r * 24;
            int n = n0 + g * 8 + r;
            float s = 0.f;
#pragma unroll
            for (int f = 0; f < 32; ++f) s += w3S[f] * xr[r][f * 24 + t];
            rhs_t[(b * Nn_ + n) * Tt_ + t] = s;
        }
        __syncthreads();
    }
    // acc index i corresponds to x offset i = f*24+t; tmp layout [b][t*32+f]
    {
        int i = tid;
        int f = i / 24, t = i - f * 24;
        atomicAdd(tmp + b * 768 + t * 32 + f, a0);
        i = tid + 256;
        f = i / 24; t = i - f * 24;
        atomicAdd(tmp + b * 768 + t * 32 + f, a1);
        i = tid + 512;
        f = i / 24; t = i - f * 24;
        atomicAdd(tmp + b * 768 + t * 32 + f, a2);
    }
}

__global__ void kc_lhs(const float* __restrict__ tmp, const float* __restrict__ w2,
                       float* __restrict__ lhs_t) {
    int tid = blockIdx.x * blockDim.x + threadIdx.x;
    int n = tid % Nn_;
    int t = (tid / Nn_) % Tt_;
    int b = tid / (Nn_ * Tt_);
    const float* tp = tmp + (b * Tt_ + t) * Ff_;
    float s = 0.f;
#pragma unroll
    for (int f = 0; f < Ff_; ++f) s += tp[f] * w2[f * Nn_ + n];
    lhs_t[(b * Tt_ + t) * Nn_ + n] = s;
}

__global__ __launch_bounds__(576) void kd_temporal(const float* __restrict__ lhs_t,
                                                   const float* __restrict__ rhs_t,
                                                   const float* __restrict__ ta_bias,
                                                   const float* __restrict__ ta_proj,
                                                   float* __restrict__ temp_w) {
    __shared__ float rl[Nn_ * Tt_];
    __shared__ float sg[Tt_ * Tt_];
    __shared__ float Eb[Tt_ * Tt_];
    int b = blockIdx.x;
    int tid = threadIdx.x;
    for (int i = tid; i < Nn_ * Tt_; i += 576) rl[i] = rhs_t[b * Nn_ * Tt_ + i];
    __syncthreads();
    int u = tid % Tt_;
    int t = tid / Tt_;
    const float* lp = lhs_t + (b * Tt_ + t) * Nn_;
    float s = 0.f;
    for (int n = 0; n < Nn_; ++n) s += lp[n] * rl[n * Tt_ + u];
    sg[t * Tt_ + u] = sigmoidf_(s + ta_bias[t * Tt_ + u]);
    __syncthreads();
    float e = 0.f;
#pragma unroll
    for (int k = 0; k < Tt_; ++k) e += ta_proj[t * Tt_ + k] * sg[k * Tt_ + u];
    Eb[t * Tt_ + u] = e;
    __syncthreads();
    if (tid < Tt_) {
        int uu = tid;
        float m = -1e30f;
        for (int s2 = 0; s2 < Tt_; ++s2) m = fmaxf(m, Eb[s2 * Tt_ + uu]);
        float sum = 0.f;
        for (int s2 = 0; s2 < Tt_; ++s2) sum += __expf(Eb[s2 * Tt_ + uu] - m);
        float inv = 1.0f / sum;
        for (int s2 = 0; s2 < Tt_; ++s2)
            temp_w[b * Tt_ * Tt_ + s2 * Tt_ + uu] = __expf(Eb[s2 * Tt_ + uu] - m) * inv;
    }
}

__global__ __launch_bounds__(256) void ke_spatial(const float* __restrict__ x,
                                                  const float* __restrict__ tw,
                                                  const float* __restrict__ sa_wa,
                                                  const float* __restrict__ sa_wb,
                                                  const float* __restrict__ sa_wc,
                                                  float* __restrict__ lhs_s,
                                                  float* __restrict__ rhs_s) {
    __shared__ float xl[Ff_ * Tt_];
    __shared__ float twl[Tt_ * Tt_];
    __shared__ float xtl[Ff_ * Tt_];
    __shared__ float tmp2[Ff_];
    int n = blockIdx.x, b = blockIdx.y, tid = threadIdx.x;
    const float* xp = x + ((size_t)(b * Nn_ + n)) * Ff_ * Tt_;
    for (int i = tid; i < Ff_ * Tt_; i += 256) xl[i] = xp[i];
    for (int i = tid; i < Tt_ * Tt_; i += 256) twl[i] = tw[b * Tt_ * Tt_ + i];
    __syncthreads();
    for (int i = tid; i < Ff_ * Tt_; i += 256) {
        int f = i / Tt_, u = i % Tt_;
        float s = 0.f;
#pragma unroll
        for (int t = 0; t < Tt_; ++t) s += xl[f * Tt_ + t] * twl[t * Tt_ + u];
        xtl[i] = s;
    }
    __syncthreads();
    if (tid < Ff_) {
        float s = 0.f;
#pragma unroll
        for (int t = 0; t < Tt_; ++t) s += xtl[tid * Tt_ + t] * sa_wa[t];
        tmp2[tid] = s;
    }
    __syncthreads();
    if (tid < Tt_) {
        float a = 0.f, r = 0.f;
#pragma unroll
        for (int f = 0; f < Ff_; ++f) {
            a += tmp2[f] * sa_wb[f * Tt_ + tid];
            r += sa_wc[f] * xtl[f * Tt_ + tid];
        }
        int o = (b * Nn_ + n) * Tt_ + tid;
        lhs_s[o] = a;
        rhs_s[o] = r;
    }
}

// attnT[b][p][m] = sigmoid(lhs_s[m].rhs_s[p] + sa_bias[m][p]) split into bf16 hi/lo
__global__ __launch_bounds__(256) void kg_attnT(const float* __restrict__ lhs_s,
                                                const float* __restrict__ rhs_s,
                                                const float* __restrict__ sa_bias,
                                                unsigned short* __restrict__ aTh,
                                                unsigned short* __restrict__ aTl) {
    __shared__ float L[256 * 25];
    __shared__ float R[16 * Tt_];
    __shared__ float Bt[256 * 17];
    int b = blockIdx.y, tid = threadIdx.x;
    int p0 = (blockIdx.x >> 1) * 16;
    int m0 = (blockIdx.x & 1) * 256;
    for (int i = tid; i < 256 * Tt_; i += 256) {
        int m = i / Tt_, t = i - m * Tt_;
        L[m * 25 + t] = lhs_s[b * Nn_ * Tt_ + (m0 + m) * Tt_ + t];
    }
    for (int i = tid; i < 16 * Tt_; i += 256) R[i] = rhs_s[b * Nn_ * Tt_ + p0 * Tt_ + i];
    for (int i = tid; i < 256 * 16; i += 256) {
        int m = i >> 4, j = i & 15;
        Bt[m * 17 + j] = sa_bias[(size_t)(m0 + m) * Nn_ + p0 + j];
    }
    __syncthreads();
    for (int idx = tid; idx < 16 * 256; idx += 256) {
        int r = idx >> 8, mm = idx & 255;
        const float* lp = L + mm * 25;
        const float* rp = R + r * Tt_;
        float s = 0.f;
#pragma unroll
        for (int t = 0; t < Tt_; ++t) s += lp[t] * rp[t];
        float v = sigmoidf_(s + Bt[mm * 17 + r]);
        unsigned short hi = f2bf(v);
        size_t o = ((size_t)b * Nn_ + p0 + r) * Nn_ + m0 + mm;
        aTh[o] = hi;
        aTl[o] = f2bf(v - bf2f(hi));
    }
}

__global__ void kprojsplit(const float* __restrict__ proj,
                           unsigned short* __restrict__ pBh,
                           unsigned short* __restrict__ pBl) {
    int i = blockIdx.x * 256 + threadIdx.x;
    float v = proj[i];
    unsigned short hi = f2bf(v);
    pBh[i] = hi;
    pBl[i] = f2bf(v - bf2f(hi));
}

// chebT[k][p][m] = cheb[k][m][p]
__global__ __launch_bounds__(256) void kchebT(const float* __restrict__ cheb,
                                              float* __restrict__ chebT) {
    __shared__ float tl[64][65];
    int p0 = blockIdx.x * 64, m0 = blockIdx.y * 64, k = blockIdx.z;
    int tid = threadIdx.x, j = tid & 63, i4 = tid >> 6;
#pragma unroll
    for (int r = 0; r < 16; ++r) {
        int i = i4 + r * 4;
        tl[i][j] = cheb[(size_t)k * Nn_ * Nn_ + (size_t)(m0 + i) * Nn_ + p0 + j];
    }
    __syncthreads();
#pragma unroll
    for (int r = 0; r < 16; ++r) {
        int pp = i4 + r * 4;
        chebT[(size_t)k * Nn_ * Nn_ + (size_t)(p0 + pp) * Nn_ + m0 + j] = tl[j][pp];
    }
}

// ST[b][p][n] = sum_m attnT[b][p][m] * proj[n][m]  via split-bf16 MFMA
// XCD-swizzled: 512 blocks = 8 XCDs x 64.
__global__ __launch_bounds__(256) void ksgemm_mfma(const unsigned short* __restrict__ aTh,
                                                   const unsigned short* __restrict__ aTl,
                                                   const unsigned short* __restrict__ pBh,
                                                   const unsigned short* __restrict__ pBl,
                                                   float* __restrict__ ST) {
    __shared__ unsigned short Ah[512 * 8], Al[512 * 8], Bh[512 * 8], Bl[512 * 8];
    int lin = blockIdx.x + 4 * (blockIdx.y + 4 * blockIdx.z);   // 0..511
    lin = (lin & 7) * 64 + (lin >> 3);                          // bijective (512%8==0)
    int nt = lin & 3;
    int pt = (lin >> 2) & 3;
    int b = lin >> 4;
    int p0 = pt * 128, n0 = nt * 128;
    int tid = threadIdx.x, wid = tid >> 6, lane = tid & 63;
    int l15 = lane & 15, l4 = lane >> 4;
    int wm = (wid & 1) * 64, wn = (wid >> 1) * 64;
    const unsigned short* Abh = aTh + (size_t)b * Nn_ * Nn_;
    const unsigned short* Abl = aTl + (size_t)b * Nn_ * Nn_;

    int cp0 = wid * 128 + lane, cp1 = cp0 + 64;
    int r0 = cp0 >> 2, k0c = (cp0 & 3) ^ ((r0 >> 1) & 3);
    int r1 = cp1 >> 2, k1c = (cp1 & 3) ^ ((r1 >> 1) & 3);
    const unsigned short* gAh0 = Abh + (size_t)(p0 + r0) * Nn_ + k0c * 8;
    const unsigned short* gAh1 = Abh + (size_t)(p0 + r1) * Nn_ + k1c * 8;
    const unsigned short* gAl0 = Abl + (size_t)(p0 + r0) * Nn_ + k0c * 8;
    const unsigned short* gAl1 = Abl + (size_t)(p0 + r1) * Nn_ + k1c * 8;
    const unsigned short* gBh0 = pBh + (size_t)(n0 + r0) * Nn_ + k0c * 8;
    const unsigned short* gBh1 = pBh + (size_t)(n0 + r1) * Nn_ + k1c * 8;
    const unsigned short* gBl0 = pBl + (size_t)(n0 + r0) * Nn_ + k0c * 8;
    const unsigned short* gBl1 = pBl + (size_t)(n0 + r1) * Nn_ + k1c * 8;
    unsigned short* lAh0 = Ah + (size_t)cp0 * 8;
    unsigned short* lAh1 = Ah + (size_t)cp1 * 8;
    unsigned short* lAl0 = Al + (size_t)cp0 * 8;
    unsigned short* lAl1 = Al + (size_t)cp1 * 8;
    unsigned short* lBh0 = Bh + (size_t)cp0 * 8;
    unsigned short* lBh1 = Bh + (size_t)cp1 * 8;
    unsigned short* lBl0 = Bl + (size_t)cp0 * 8;
    unsigned short* lBl1 = Bl + (size_t)cp1 * 8;

    int ca[4], cb[4];
#pragma unroll
    for (int i = 0; i < 4; ++i) {
        int row = wm + i * 16 + l15;
        ca[i] = row * 4 + (l4 ^ ((row >> 1) & 3));
        row = wn + i * 16 + l15;
        cb[i] = row * 4 + (l4 ^ ((row >> 1) & 3));
    }

    f32x4 acc[4][4];
#pragma unroll
    for (int i = 0; i < 4; ++i)
#pragma unroll
        for (int j = 0; j < 4; ++j) acc[i][j] = (f32x4){0.f, 0.f, 0.f, 0.f};

    for (int ks = 0; ks < 16; ++ks) {
        __syncthreads();
        async16(gAh0 + ks * 32, lAh0);
        async16(gAh1 + ks * 32, lAh1);
        async16(gAl0 + ks * 32, lAl0);
        async16(gAl1 + ks * 32, lAl1);
        async16(gBh0 + ks * 32, lBh0);
        async16(gBh1 + ks * 32, lBh1);
        async16(gBl0 + ks * 32, lBl0);
        async16(gBl1 + ks * 32, lBl1);
        __syncthreads();
        bf16x8 ah[4], al[4], bh[4], bl[4];
#pragma unroll
        for (int i = 0; i < 4; ++i) {
            ah[i] = *(const bf16x8*)(Ah + (size_t)ca[i] * 8);
            al[i] = *(const bf16x8*)(Al + (size_t)ca[i] * 8);
        }
#pragma unroll
        for (int j = 0; j < 4; ++j) {
            bh[j] = *(const bf16x8*)(Bh + (size_t)cb[j] * 8);
            bl[j] = *(const bf16x8*)(Bl + (size_t)cb[j] * 8);
        }
#pragma unroll
        for (int i = 0; i < 4; ++i)
#pragma unroll
            for (int j = 0; j < 4; ++j) {
                acc[i][j] = __builtin_amdgcn_mfma_f32_16x16x32_bf16(ah[i], bh[j], acc[i][j], 0, 0, 0);
                acc[i][j] = __builtin_amdgcn_mfma_f32_16x16x32_bf16(ah[i], bl[j], acc[i][j], 0, 0, 0);
                acc[i][j] = __builtin_amdgcn_mfma_f32_16x16x32_bf16(al[i], bh[j], acc[i][j], 0, 0, 0);
            }
    }

    float* Cb = ST + (size_t)b * Nn_ * Nn_;
#pragma unroll
    for (int i = 0; i < 4; ++i)
#pragma unroll
        for (int j = 0; j < 4; ++j) {
            int p = p0 + wm + i * 16 + l4 * 4;
            int n = n0 + wn + j * 16 + l15;
#pragma unroll
            for (int r = 0; r < 4; ++r)
                Cb[(size_t)(p + r) * Nn_ + n] = acc[i][j][r];
        }
}

// fused row-softmax + cheb multiply + bf16 AT write (one wave per ST row)
__global__ __launch_bounds__(256) void kjaT(const float* __restrict__ ST,
                                            const float* __restrict__ chebT,
                                            unsigned short* __restrict__ AT) {
    int row = blockIdx.x * 4 + (threadIdx.x >> 6);   // b*512 + p
    int lane = threadIdx.x & 63;
    const float* rp = ST + (size_t)row * Nn_ + lane * 8;
    float4 a = *(const float4*)rp;
    float4 c = *(const float4*)(rp + 4);
    float m = fmaxf(fmaxf(fmaxf(a.x, a.y), fmaxf(a.z, a.w)),
                    fmaxf(fmaxf(c.x, c.y), fmaxf(c.z, c.w)));
#pragma unroll
    for (int off = 32; off > 0; off >>= 1) m = fmaxf(m, __shfl_xor(m, off, 64));
    float e[8];
    e[0] = __expf(a.x - m); e[1] = __expf(a.y - m); e[2] = __expf(a.z - m); e[3] = __expf(a.w - m);
    e[4] = __expf(c.x - m); e[5] = __expf(c.y - m); e[6] = __expf(c.z - m); e[7] = __expf(c.w - m);
    float s = e[0] + e[1] + e[2] + e[3] + e[4] + e[5] + e[6] + e[7];
#pragma unroll
    for (int off = 32; off > 0; off >>= 1) s += __shfl_xor(s, off, 64);
    float inv = 1.0f / s;
#pragma unroll
    for (int i = 0; i < 8; ++i) e[i] *= inv;
    int b = row >> 9, p = row & 511;
#pragma unroll
    for (int k = 0; k < 3; ++k) {
        const float* cp = chebT + (size_t)k * 262144 + (size_t)p * Nn_ + lane * 8;
        float4 c0 = *(const float4*)cp;
        float4 c1 = *(const float4*)(cp + 4);
        u16x4 o0, o1;
        o0[0] = f2bf(c0.x * e[0]); o0[1] = f2bf(c0.y * e[1]);
        o0[2] = f2bf(c0.z * e[2]); o0[3] = f2bf(c0.w * e[3]);
        o1[0] = f2bf(c1.x * e[4]); o1[1] = f2bf(c1.y * e[5]);
        o1[2] = f2bf(c1.z * e[6]); o1[3] = f2bf(c1.w * e[7]);
        unsigned short* op = AT + (size_t)k * 8388608 + (size_t)b * 262144 + (size_t)p * Nn_ + lane * 8;
        *(u16x4*)op = o0;
        *(u16x4*)(op + 4) = o1;
    }
}

// XT[b][q][m] bf16 = x[b][m][q]
__global__ __launch_bounds__(256) void kxT(const float* __restrict__ x,
                                           unsigned short* __restrict__ XT) {
    __shared__ float tl[64][65];
    int q0 = blockIdx.x * 64, m0 = blockIdx.y * 64, b = blockIdx.z;
    int tid = threadIdx.x, j = tid & 63, i4 = tid >> 6;
#pragma unroll
    for (int r = 0; r < 16; ++r) {
        int i = i4 + r * 4;
        tl[i][j] = x[((size_t)(b * Nn_ + m0 + i)) * 768 + q0 + j];
    }
    __syncthreads();
#pragma unroll
    for (int r = 0; r < 16; ++r) {
        int qq = i4 + r * 4;
        XT[((size_t)b * 768 + q0 + qq) * Nn_ + m0 + j] = f2bf(tl[j][qq]);
    }
}

// H[b][p][q] bf16 = sum_m AT_k[b][p][m] * XT[b][q][m]; grid.z = k*32+b (3 k fused)
// XCD-swizzled: 2304 blocks = 8 XCDs x 288.
__global__ __launch_bounds__(256) void hgemm_mfma(const unsigned short* __restrict__ AT,
                                                  const unsigned short* __restrict__ XT,
                                                  unsigned short* __restrict__ H) {
    __shared__ unsigned short As[512 * 8];
    __shared__ unsigned short Bs[512 * 8];
    int lin = blockIdx.x + 6 * (blockIdx.y + 4 * blockIdx.z);   // 0..2303
    lin = (lin & 7) * 288 + (lin >> 3);                         // bijective (2304%8==0)
    int qt = lin % 6;
    int rem = lin / 6;
    int pt = rem & 3;
    int bz = rem >> 2;
    int b = bz & 31, kk2 = bz >> 5;
    int p0 = pt * 128;
    int q0 = qt * 128;
    int tid = threadIdx.x;
    int wid = tid >> 6, lane = tid & 63;
    int l15 = lane & 15, l4 = lane >> 4;
    int wm = (wid & 1) * 64, wn = (wid >> 1) * 64;
    const unsigned short* Ab = AT + (size_t)kk2 * 8388608 + (size_t)b * Nn_ * Nn_;
    const unsigned short* Bb = XT + (size_t)b * 768 * Nn_;

    int cp0 = wid * 128 + lane;
    int cp1 = cp0 + 64;
    int rA0 = cp0 >> 2, kA0 = (cp0 & 3) ^ ((rA0 >> 1) & 3);
    int rA1 = cp1 >> 2, kA1 = (cp1 & 3) ^ ((rA1 >> 1) & 3);
    const unsigned short* gA0 = Ab + (size_t)(p0 + rA0) * Nn_ + kA0 * 8;
    const unsigned short* gA1 = Ab + (size_t)(p0 + rA1) * Nn_ + kA1 * 8;
    const unsigned short* gB0 = Bb + (size_t)(q0 + rA0) * Nn_ + kA0 * 8;
    const unsigned short* gB1 = Bb + (size_t)(q0 + rA1) * Nn_ + kA1 * 8;
    unsigned short* lA0 = As + (size_t)(wid * 128) * 8;
    unsigned short* lA1 = As + (size_t)(wid * 128 + 64) * 8;
    unsigned short* lB0 = Bs + (size_t)(wid * 128) * 8;
    unsigned short* lB1 = Bs + (size_t)(wid * 128 + 64) * 8;

    int ca[4], cb[4];
#pragma unroll
    for (int i = 0; i < 4; ++i) {
        int row = wm + i * 16 + l15;
        ca[i] = row * 4 + (l4 ^ ((row >> 1) & 3));
        row = wn + i * 16 + l15;
        cb[i] = row * 4 + (l4 ^ ((row >> 1) & 3));
    }

    f32x4 acc[4][4];
#pragma unroll
    for (int i = 0; i < 4; ++i)
#pragma unroll
        for (int j = 0; j < 4; ++j) acc[i][j] = (f32x4){0.f, 0.f, 0.f, 0.f};

    for (int ks = 0; ks < 16; ++ks) {
        __syncthreads();
        async16(gA0 + ks * 32, lA0);
        async16(gA1 + ks * 32, lA1);
        async16(gB0 + ks * 32, lB0);
        async16(gB1 + ks * 32, lB1);
        __syncthreads();
        bf16x8 af[4], bfv[4];
#pragma unroll
        for (int i = 0; i < 4; ++i) af[i] = *(const bf16x8*)(As + (size_t)ca[i] * 8);
#pragma unroll
        for (int j = 0; j < 4; ++j) bfv[j] = *(const bf16x8*)(Bs + (size_t)cb[j] * 8);
#pragma unroll
        for (int i = 0; i < 4; ++i)
#pragma unroll
            for (int j = 0; j < 4; ++j)
                acc[i][j] = __builtin_amdgcn_mfma_f32_16x16x32_bf16(af[i], bfv[j], acc[i][j], 0, 0, 0);
    }

    unsigned short* Hb = H + (size_t)kk2 * HS_ + (size_t)b * Nn_ * 768;
#pragma unroll
    for (int i = 0; i < 4; ++i)
#pragma unroll
        for (int j = 0; j < 4; ++j) {
            int p = p0 + wm + i * 16 + l4 * 4;
            int q = q0 + wn + j * 16 + l15;
#pragma unroll
            for (int r = 0; r < 4; ++r)
                Hb[(size_t)(p + r) * 768 + q] = f2bf(acc[i][j][r]);
        }
}

// prep: WA[r][kf] bf16 (kf<96: w_cheb[kf][r]; kf>=96: skip_w[r][kf-96])
//       WC[(j*64+c)][g] bf16 = time_w[c][g][j]; also zero tmp for kab atomics
__global__ void kprep(const float* __restrict__ wch, const float* __restrict__ skw,
                      const float* __restrict__ tw,
                      unsigned short* __restrict__ WA, unsigned short* __restrict__ WC,
                      float* __restrict__ tmp) {
    int tid = threadIdx.x;
    for (int i = tid; i < 64 * 128; i += 256) {
        int r = i >> 7, kf = i & 127;
        float v = (kf < 96) ? wch[kf * 64 + r] : skw[r * 32 + (kf - 96)];
        WA[i] = f2bf(v);
    }
    for (int i = tid; i < 192 * 64; i += 256) {
        int j = i / 4096, c = (i >> 6) & 63, g = i & 63;
        WC[i] = f2bf(tw[c * 192 + g * 3 + j]);
    }
    for (int i = tid; i < 24576; i += 256) tmp[i] = 0.f;
}

// Staging macros for ktail: NAMED registers only (no arrays, no lambdas) so
// the compiler keeps the staged tile in VGPRs. R9's rg[3][4]+lambda version
// spilled to scratch (FETCH +220MB, WRITE +170MB, VGPR=64) — rule #20 family.
#define LOADU(utg_, un_, ufg_, uk_, R0, R1, R2, R3, n0_)                                  \
    do {                                                                                  \
        int t0_ = (utg_) * 4, f0_ = (ufg_) * 4;                                           \
        if ((uk_) < 3) {                                                                  \
            const unsigned short* hp_ = H + (size_t)(uk_) * HS_ +                         \
                ((size_t)b * Nn_ + (n0_) + (un_)) * 768 + f0_ * 24 + t0_;                 \
            R0 = *(const u16x4*)hp_;                                                      \
            R1 = *(const u16x4*)(hp_ + 24);                                               \
            R2 = *(const u16x4*)(hp_ + 48);                                               \
            R3 = *(const u16x4*)(hp_ + 72);                                               \
        } else {                                                                          \
            const float* xp_ = x + ((size_t)b * Nn_ + (n0_) + (un_)) * 768 + f0_ * 24 + t0_; \
            float4 v0_ = *(const float4*)xp_;                                             \
            float4 v1_ = *(const float4*)(xp_ + 24);                                      \
            float4 v2_ = *(const float4*)(xp_ + 48);                                      \
            float4 v3_ = *(const float4*)(xp_ + 72);                                      \
            R0 = (u16x4){f2bf(v0_.x), f2bf(v0_.y), f2bf(v0_.z), f2bf(v0_.w)};             \
            R1 = (u16x4){f2bf(v1_.x), f2bf(v1_.y), f2bf(v1_.z), f2bf(v1_.w)};             \
            R2 = (u16x4){f2bf(v2_.x), f2bf(v2_.y), f2bf(v2_.z), f2bf(v2_.w)};             \
            R3 = (u16x4){f2bf(v3_.x), f2bf(v3_.y), f2bf(v3_.z), f2bf(v3_.w)};             \
        }                                                                                 \
    } while (0)

#define WRITEU(utg_, un_, ufg_, uk_, R0, R1, R2, R3)                                      \
    do {                                                                                  \
        int t0_ = (utg_) * 4;                                                             \
        int kc4_ = (uk_) * 4 + ((ufg_) >> 1);                                             \
        int half_ = (ufg_) & 1;                                                           \
        int c0_ = (un_) * 24 + t0_;                                                       \
        int p0_ = (c0_ + 0) * 16 + (kc4_ ^ (((c0_ + 0) ^ ((c0_ + 0) >> 2)) & 7));         \
        int p1_ = (c0_ + 1) * 16 + (kc4_ ^ (((c0_ + 1) ^ ((c0_ + 1) >> 2)) & 7));         \
        int p2_ = (c0_ + 2) * 16 + (kc4_ ^ (((c0_ + 2) ^ ((c0_ + 2) >> 2)) & 7));         \
        int p3_ = (c0_ + 3) * 16 + (kc4_ ^ (((c0_ + 3) ^ ((c0_ + 3) >> 2)) & 7));         \
        *(u16x4*)(Hl + p0_ * 8 + half_ * 4) = (u16x4){R0[0], R1[0], R2[0], R3[0]};        \
        *(u16x4*)(Hl + p1_ * 8 + half_ * 4) = (u16x4){R0[1], R1[1], R2[1], R3[1]};        \
        *(u16x4*)(Hl + p2_ * 8 + half_ * 4) = (u16x4){R0[2], R1[2], R2[2], R3[2]};        \
        *(u16x4*)(Hl + p3_ * 8 + half_ * 4) = (u16x4){R0[3], R1[3], R2[3], R3[3]};        \
    } while (0)

#define REGLOAD(n0_)                                         \
    do {                                                     \
        LOADU(utg0, un0, ufg0, uk0, rA0, rA1, rA2, rA3, n0_);\
        LOADU(utg1, un1, ufg1, uk1, rB0, rB1, rB2, rB3, n0_);\
        LOADU(utg2, un2, ufg2, uk2, rC0, rC1, rC2, rC3, n0_);\
    } while (0)

#define HLWRITE()                                            \
    do {                                                     \
        WRITEU(utg0, un0, ufg0, uk0, rA0, rA1, rA2, rA3);    \
        WRITEU(utg1, un1, ufg1, uk1, rB0, rB1, rB2, rB3);    \
        WRITEU(utg2, un2, ufg2, uk2, rC0, rC1, rC2, rC3);    \
    } while (0)

// -------- fused tail, 4-tile persistent blocks (scratch-spill FIXED):
// weight frags once per block; tile i+1's H/x data staged in NAMED VGPRs
// during tile i's compute, written to Hl after the stage1 barrier.
// Grid 32x32 = 1024 blocks = 4/CU, one co-residency round. --
__global__ __launch_bounds__(256, 4) void ktail(const unsigned short* __restrict__ H,
                                                const float* __restrict__ x,
                                                const unsigned short* __restrict__ WA,
                                                const unsigned short* __restrict__ WC,
                                                const float* __restrict__ time_b,
                                                const float* __restrict__ skip_b,
                                                const float* __restrict__ ln_g,
                                                const float* __restrict__ ln_b,
                                                float* __restrict__ out) {
    __shared__ __align__(16) unsigned short Hl[96 * 16 * 8];   // 96 cols x 16 chunks x 8 shorts
    __shared__ __align__(16) unsigned short Gl[104 * 64];      // 104 rows x 8 chunks x 8 shorts
    __shared__ float biasS[64], lgS[64], lbS[64];
    __shared__ float muS[96], rsS[96];

    int b = blockIdx.y;
    int nb = blockIdx.x * 16;          // 4 tiles: n0 = nb + tc*4
    int tid = threadIdx.x;
    int w = tid >> 6, lane = tid & 63, l15 = lane & 15, l4 = lane >> 4;

    // weight fragments (once per block, amortized over 4 tiles)
    bf16x8 af[4], cf[3][2];
#pragma unroll
    for (int q = 0; q < 4; ++q)
        af[q] = *(const bf16x8*)(WA + (size_t)(16 * w + l15) * 128 + q * 32 + l4 * 8);
#pragma unroll
    for (int j = 0; j < 3; ++j)
#pragma unroll
        for (int kc = 0; kc < 2; ++kc)
            cf[j][kc] = *(const bf16x8*)(WC + (size_t)(j * 64 + 16 * w + l15) * 64 + kc * 32 + l4 * 8);

    // per-thread staging-unit decode (tile-invariant): u = (((k*8+fg)*4+n)*6+tg)
    int u0 = tid, u1 = 256 + tid, u2 = 512 + tid;
    int utg0 = u0 % 6, un0 = (u0 / 6) & 3, ufg0 = (u0 / 24) & 7, uk0 = u0 / 192;
    int utg1 = u1 % 6, un1 = (u1 / 6) & 3, ufg1 = (u1 / 24) & 7, uk1 = u1 / 192;
    int utg2 = u2 % 6, un2 = (u2 / 6) & 3, ufg2 = (u2 / 24) & 7, uk2 = u2 / 192;

    u16x4 rA0, rA1, rA2, rA3, rB0, rB1, rB2, rB3, rC0, rC1, rC2, rC3;

    // prologue: tile 0 staged; borders + params
    REGLOAD(nb);
    if (tid < 64) {
        int n = tid >> 4, rr = (tid >> 3) & 1, gc = tid & 7;
        int row = n * 26 + rr * 25;
        int posg = row * 8 + (gc ^ (row & 7));
        *(float4*)(void*)(Gl + posg * 8) = make_float4(0.f, 0.f, 0.f, 0.f);
        biasS[tid] = time_b[tid] + skip_b[tid];
        lgS[tid] = ln_g[tid];
        lbS[tid] = ln_b[tid];
    }
    HLWRITE();
    __syncthreads();
    REGLOAD(nb + 4);   // tile 1 in flight during tile 0 stage1

#pragma unroll
    for (int tc = 0; tc < 4; ++tc) {
        int n0 = nb + tc * 4;

        // stage 1: gcn (K=96) + skip (K=32), relu(gcn) -> Gl bf16
        f32x4 accs[6];
#pragma unroll
        for (int ct = 0; ct < 6; ++ct) {
            int col = ct * 16 + l15;
            int cx = (col ^ (col >> 2)) & 7;
            bf16x8 h0 = *(const bf16x8*)(Hl + (col * 16 + ((0 + l4) ^ cx)) * 8);
            bf16x8 h1 = *(const bf16x8*)(Hl + (col * 16 + ((4 + l4) ^ cx)) * 8);
            bf16x8 h2 = *(const bf16x8*)(Hl + (col * 16 + ((8 + l4) ^ cx)) * 8);
            bf16x8 h3 = *(const bf16x8*)(Hl + (col * 16 + ((12 + l4) ^ cx)) * 8);
            f32x4 g = (f32x4){0.f, 0.f, 0.f, 0.f};
            g = __builtin_amdgcn_mfma_f32_16x16x32_bf16(af[0], h0, g, 0, 0, 0);
            g = __builtin_amdgcn_mfma_f32_16x16x32_bf16(af[1], h1, g, 0, 0, 0);
            g = __builtin_amdgcn_mfma_f32_16x16x32_bf16(af[2], h2, g, 0, 0, 0);
            f32x4 s = (f32x4){0.f, 0.f, 0.f, 0.f};
            s = __builtin_amdgcn_mfma_f32_16x16x32_bf16(af[3], h3, s, 0, 0, 0);
            accs[ct] = s;
            int n = col / 24, t = col - n * 24;
            int row = n * 26 + t + 1;
            int gc = 2 * w + (l4 >> 1);
            int posg = row * 8 + (gc ^ (row & 7));
            u16x4 pk;
#pragma unroll
            for (int r = 0; r < 4; ++r) pk[r] = f2bf(g[r] > 0.f ? g[r] : 0.f);
            *(u16x4*)(Gl + posg * 8 + (l4 & 1) * 4) = pk;
        }
        __syncthreads();   // B: Hl reads + Gl writes complete

        // write next tile's staged regs into Hl; refill regs with tile tc+2
        if (tc < 3) {
            HLWRITE();
            if (tc < 2) REGLOAD(nb + (tc + 2) * 4);
        }

        // stage 2: conv as 3 shifted GEMMs (K=64) + skip + bias + relu -> regs
        f32x4 oo[6];
        float ps6[6], pq6[6];
#pragma unroll
        for (int ct = 0; ct < 6; ++ct) {
            int col = ct * 16 + l15;
            int n = col / 24, t = col - n * 24;
            f32x4 acc = accs[ct];
#pragma unroll
            for (int j = 0; j < 3; ++j) {
                int row = n * 26 + t + j;
                int rx = row & 7;
                bf16x8 g0 = *(const bf16x8*)(Gl + (row * 8 + (l4 ^ rx)) * 8);
                bf16x8 g1 = *(const bf16x8*)(Gl + (row * 8 + ((l4 + 4) ^ rx)) * 8);
                acc = __builtin_amdgcn_mfma_f32_16x16x32_bf16(cf[j][0], g0, acc, 0, 0, 0);
                acc = __builtin_amdgcn_mfma_f32_16x16x32_bf16(cf[j][1], g1, acc, 0, 0, 0);
            }
            int cb = 16 * w + 4 * l4;
            f32x4 bv = *(const f32x4*)(biasS + cb);
            f32x4 o;
#pragma unroll
            for (int r = 0; r < 4; ++r) {
                float v = acc[r] + bv[r];
                o[r] = v > 0.f ? v : 0.f;
            }
            oo[ct] = o;
            float ps = o[0] + o[1] + o[2] + o[3];
            float pq = o[0] * o[0] + o[1] * o[1] + o[2] * o[2] + o[3] * o[3];
            ps += __shfl_xor(ps, 16, 64);
            ps += __shfl_xor(ps, 32, 64);
            pq += __shfl_xor(pq, 16, 64);
            pq += __shfl_xor(pq, 32, 64);
            ps6[ct] = ps;
            pq6[ct] = pq;
        }
        __syncthreads();   // C: Gl reads done -> rows 0..23 reusable as LN scratch

        float* lnP = (float*)Gl;   // [0..383] sums, [384..767] sq-sums (w*96+col)
        if (l4 == 0) {
#pragma unroll
            for (int ct = 0; ct < 6; ++ct) {
                int col = ct * 16 + l15;
                lnP[w * 96 + col] = ps6[ct];
                lnP[384 + w * 96 + col] = pq6[ct];
            }
        }
        __syncthreads();   // D
        if (tid < 96) {
            float s = lnP[tid] + lnP[96 + tid] + lnP[192 + tid] + lnP[288 + tid];
            float q = lnP[384 + tid] + lnP[480 + tid] + lnP[576 + tid] + lnP[672 + tid];
            float mu = s * (1.0f / 64.0f);
            float var = q * (1.0f / 64.0f) - mu * mu;
            muS[tid] = mu;
            rsS[tid] = rsqrtf(var + 1e-5f);
        }
        __syncthreads();   // E

        // direct register store: out[((b*N+n)*64+c)*24+t], c = 16w+4*l4+r
        float* ob = out + ((size_t)b * Nn_ + n0) * (TC_ * Tt_);
        int cb = 16 * w + 4 * l4;
        f32x4 lgv = *(const f32x4*)(lgS + cb);
        f32x4 lbv = *(const f32x4*)(lbS + cb);
#pragma unroll
        for (int ct = 0; ct < 6; ++ct) {
            int col = ct * 16 + l15;
            int n = col / 24, t = col - n * 24;
            float mu = muS[col], rs = rsS[col];
            f32x4 o = oo[ct];
            float* op = ob + (size_t)(n * 64 + cb) * 24 + t;
#pragma unroll
            for (int r = 0; r < 4; ++r)
                op[r * 24] = (o[r] - mu) * rs * lgv[r] + lbv[r];
        }
        // re-zero Gl row 0 (border clobbered by lnP); protected by next barrier B
        if (tc < 3 && tid < 8)
            *(float4*)(void*)(Gl + tid * 8) = make_float4(0.f, 0.f, 0.f, 0.f);
    }
}

extern "C" void kernel_launch(void* const* d_in, const int* in_sizes, int n_in,
                              void* d_out, int out_size, void* d_ws, size_t ws_size,
                              hipStream_t stream) {
    const float* x       = (const float*)d_in[0];
    const float* cheb    = (const float*)d_in[1];
    const float* w_cheb  = (const float*)d_in[2];
    const float* sa_wa   = (const float*)d_in[3];
    const float* sa_wb   = (const float*)d_in[4];
    const float* sa_wc   = (const float*)d_in[5];
    const float* sa_bias = (const float*)d_in[6];
    const float* sa_proj = (const float*)d_in[7];
    const float* ta_w1   = (const float*)d_in[8];
    const float* ta_w2   = (const float*)d_in[9];
    const float* ta_w3   = (const float*)d_in[10];
    const float* ta_bias = (const float*)d_in[11];
    const float* ta_proj = (const float*)d_in[12];
    const float* time_w  = (const float*)d_in[13];
    const float* time_b  = (const float*)d_in[14];
    const float* skip_w  = (const float*)d_in[15];
    const float* skip_b  = (const float*)d_in[16];
    const float* ln_g    = (const float*)d_in[17];
    const float* ln_b    = (const float*)d_in[18];
    float* out = (float*)d_out;

    // ---- workspace layout (~195 MB) ----
    float* cur   = (float*)d_ws;
    float* tmp   = cur;            cur += 24576;
    float* lhs_t = cur;            cur += 393216;
    float* rhs_t = cur;            cur += 393216;
    float* tw    = cur;            cur += 18432;
    float* lhs_s = cur;            cur += 393216;
    float* rhs_s = cur;            cur += 393216;
    unsigned short* WAbuf = (unsigned short*)cur;            // 8192 us
    unsigned short* WCbuf = WAbuf + 8192;                    // 12288 us
    cur += 10240;
    unsigned short* pBh = (unsigned short*)cur;              // 262144 us
    unsigned short* pBl = pBh + 262144;                      // 262144 us
    cur += 262144;
    float* chebT = cur;            cur += 786432;
    unsigned short* regionA = (unsigned short*)cur;          // attnT hi/lo, then AT x3
    unsigned short* aTh = regionA;
    unsigned short* aTl = regionA + 8388608;
    unsigned short* ATb = regionA;
    cur += 12582912;
    float* STbuf = cur;            cur += 8388608;
    unsigned short* XT = (unsigned short*)cur;               // 12582912 us
    cur += 6291456;
    unsigned short* hbuf = (unsigned short*)cur;             // 37748736 us

    kprep<<<1, 256, 0, stream>>>(w_cheb, skip_w, time_w, WAbuf, WCbuf, tmp);
    kprojsplit<<<1024, 256, 0, stream>>>(sa_proj, pBh, pBl);
    kchebT<<<dim3(8, 8, 3), 256, 0, stream>>>(cheb, chebT);
    kxT<<<dim3(12, 8, 32), 256, 0, stream>>>(x, XT);
    kab<<<dim3(16, 32), 256, 0, stream>>>(x, ta_w1, ta_w3, tmp, rhs_t);
    kc_lhs<<<1536, 256, 0, stream>>>(tmp, ta_w2, lhs_t);
    kd_temporal<<<32, 576, 0, stream>>>(lhs_t, rhs_t, ta_bias, ta_proj, tw);
    ke_spatial<<<dim3(512, 32), 256, 0, stream>>>(x, tw, sa_wa, sa_wb, sa_wc, lhs_s, rhs_s);
    kg_attnT<<<dim3(64, 32), 256, 0, stream>>>(lhs_s, rhs_s, sa_bias, aTh, aTl);
    ksgemm_mfma<<<dim3(4, 4, 32), 256, 0, stream>>>(aTh, aTl, pBh, pBl, STbuf);
    kjaT<<<4096, 256, 0, stream>>>(STbuf, chebT, ATb);
    hgemm_mfma<<<dim3(6, 4, 96), 256, 0, stream>>>(ATb, XT, hbuf);
    ktail<<<dim3(32, 32), 256, 0, stream>>>(hbuf, x, WAbuf, WCbuf,
                                            time_b, skip_b, ln_g, ln_b, out);
}

// Round 11
// 438.447 us; speedup vs baseline: 1.3421x; 1.2893x over previous
//
#include <hip/hip_runtime.h>
#include <math.h>

#define Bb_ 32
#define Nn_ 512
#define Ff_ 32
#define Tt_ 24
#define GC_ 64
#define TC_ 64
#define HS_ 12582912

typedef __attribute__((ext_vector_type(8))) short bf16x8;
typedef __attribute__((ext_vector_type(4))) float f32x4;
typedef __attribute__((ext_vector_type(8))) unsigned short u16x8;
typedef __attribute__((ext_vector_type(4))) unsigned short u16x4;

__device__ __forceinline__ float sigmoidf_(float v) { return 1.0f / (1.0f + __expf(-v)); }

__device__ __forceinline__ unsigned short f2bf(float f) {
    unsigned u = __float_as_uint(f);
    u = (u + 0x7fffu + ((u >> 16) & 1u)) >> 16;
    return (unsigned short)u;
}
__device__ __forceinline__ float bf2f(unsigned short h) {
    return __uint_as_float(((unsigned)h) << 16);
}

__device__ __forceinline__ void async16(const void* g, void* l) {
    __builtin_amdgcn_global_load_lds((const __attribute__((address_space(1))) unsigned int*)g,
                                     (__attribute__((address_space(3))) unsigned int*)l,
                                     16, 0, 0);
}

// fused ka_tmp + kb_rhs: one pass over x, 8-row groups.
__global__ __launch_bounds__(256) void kab(const float* __restrict__ x,
                                           const float* __restrict__ w1,
                                           const float* __restrict__ w3,
                                           float* __restrict__ tmp,
                                           float* __restrict__ rhs_t) {
    __shared__ float xr[8][768];
    __shared__ float w3S[32];
    int b = blockIdx.y, n0 = blockIdx.x * 32, tid = threadIdx.x;
    if (tid < 32) w3S[tid] = w3[tid];
    float a0 = 0.f, a1 = 0.f, a2 = 0.f;
    for (int g = 0; g < 4; ++g) {
#pragma unroll
        for (int r = 0; r < 8; ++r) {
            int n = n0 + g * 8 + r;
            const float* xp = x + ((size_t)(b * Nn_ + n)) * 768;
            float v0 = xp[tid], v1 = xp[tid + 256], v2 = xp[tid + 512];
            float w = w1[n];
            a0 += w * v0;
            a1 += w * v1;
            a2 += w * v2;
            xr[r][tid] = v0;
            xr[r][tid + 256] = v1;
            xr[r][tid + 512] = v2;
        }
        __syncthreads();
        if (tid < 192) {
            int r = tid / 24, t = tid - r * 24;
            int n = n0 + g * 8 + r;
            float s = 0.f;
#pragma unroll
            for (int f = 0; f < 32; ++f) s += w3S[f] * xr[r][f * 24 + t];
            rhs_t[(b * Nn_ + n) * Tt_ + t] = s;
        }
        __syncthreads();
    }
    // acc index i corresponds to x offset i = f*24+t; tmp layout [b][t*32+f]
    {
        int i = tid;
        int f = i / 24, t = i - f * 24;
        atomicAdd(tmp + b * 768 + t * 32 + f, a0);
        i = tid + 256;
        f = i / 24; t = i - f * 24;
        atomicAdd(tmp + b * 768 + t * 32 + f, a1);
        i = tid + 512;
        f = i / 24; t = i - f * 24;
        atomicAdd(tmp + b * 768 + t * 32 + f, a2);
    }
}

__global__ void kc_lhs(const float* __restrict__ tmp, const float* __restrict__ w2,
                       float* __restrict__ lhs_t) {
    int tid = blockIdx.x * blockDim.x + threadIdx.x;
    int n = tid % Nn_;
    int t = (tid / Nn_) % Tt_;
    int b = tid / (Nn_ * Tt_);
    const float* tp = tmp + (b * Tt_ + t) * Ff_;
    float s = 0.f;
#pragma unroll
    for (int f = 0; f < Ff_; ++f) s += tp[f] * w2[f * Nn_ + n];
    lhs_t[(b * Tt_ + t) * Nn_ + n] = s;
}

__global__ __launch_bounds__(576) void kd_temporal(const float* __restrict__ lhs_t,
                                                   const float* __restrict__ rhs_t,
                                                   const float* __restrict__ ta_bias,
                                                   const float* __restrict__ ta_proj,
                                                   float* __restrict__ temp_w) {
    __shared__ float rl[Nn_ * Tt_];
    __shared__ float sg[Tt_ * Tt_];
    __shared__ float Eb[Tt_ * Tt_];
    int b = blockIdx.x;
    int tid = threadIdx.x;
    for (int i = tid; i < Nn_ * Tt_; i += 576) rl[i] = rhs_t[b * Nn_ * Tt_ + i];
    __syncthreads();
    int u = tid % Tt_;
    int t = tid / Tt_;
    const float* lp = lhs_t + (b * Tt_ + t) * Nn_;
    float s = 0.f;
    for (int n = 0; n < Nn_; ++n) s += lp[n] * rl[n * Tt_ + u];
    sg[t * Tt_ + u] = sigmoidf_(s + ta_bias[t * Tt_ + u]);
    __syncthreads();
    float e = 0.f;
#pragma unroll
    for (int k = 0; k < Tt_; ++k) e += ta_proj[t * Tt_ + k] * sg[k * Tt_ + u];
    Eb[t * Tt_ + u] = e;
    __syncthreads();
    if (tid < Tt_) {
        int uu = tid;
        float m = -1e30f;
        for (int s2 = 0; s2 < Tt_; ++s2) m = fmaxf(m, Eb[s2 * Tt_ + uu]);
        float sum = 0.f;
        for (int s2 = 0; s2 < Tt_; ++s2) sum += __expf(Eb[s2 * Tt_ + uu] - m);
        float inv = 1.0f / sum;
        for (int s2 = 0; s2 < Tt_; ++s2)
            temp_w[b * Tt_ * Tt_ + s2 * Tt_ + uu] = __expf(Eb[s2 * Tt_ + uu] - m) * inv;
    }
}

__global__ __launch_bounds__(256) void ke_spatial(const float* __restrict__ x,
                                                  const float* __restrict__ tw,
                                                  const float* __restrict__ sa_wa,
                                                  const float* __restrict__ sa_wb,
                                                  const float* __restrict__ sa_wc,
                                                  float* __restrict__ lhs_s,
                                                  float* __restrict__ rhs_s) {
    __shared__ float xl[Ff_ * Tt_];
    __shared__ float twl[Tt_ * Tt_];
    __shared__ float xtl[Ff_ * Tt_];
    __shared__ float tmp2[Ff_];
    int n = blockIdx.x, b = blockIdx.y, tid = threadIdx.x;
    const float* xp = x + ((size_t)(b * Nn_ + n)) * Ff_ * Tt_;
    for (int i = tid; i < Ff_ * Tt_; i += 256) xl[i] = xp[i];
    for (int i = tid; i < Tt_ * Tt_; i += 256) twl[i] = tw[b * Tt_ * Tt_ + i];
    __syncthreads();
    for (int i = tid; i < Ff_ * Tt_; i += 256) {
        int f = i / Tt_, u = i % Tt_;
        float s = 0.f;
#pragma unroll
        for (int t = 0; t < Tt_; ++t) s += xl[f * Tt_ + t] * twl[t * Tt_ + u];
        xtl[i] = s;
    }
    __syncthreads();
    if (tid < Ff_) {
        float s = 0.f;
#pragma unroll
        for (int t = 0; t < Tt_; ++t) s += xtl[tid * Tt_ + t] * sa_wa[t];
        tmp2[tid] = s;
    }
    __syncthreads();
    if (tid < Tt_) {
        float a = 0.f, r = 0.f;
#pragma unroll
        for (int f = 0; f < Ff_; ++f) {
            a += tmp2[f] * sa_wb[f * Tt_ + tid];
            r += sa_wc[f] * xtl[f * Tt_ + tid];
        }
        int o = (b * Nn_ + n) * Tt_ + tid;
        lhs_s[o] = a;
        rhs_s[o] = r;
    }
}

// attnT[b][p][m] = sigmoid(lhs_s[m].rhs_s[p] + sa_bias[m][p]) split into bf16 hi/lo
__global__ __launch_bounds__(256) void kg_attnT(const float* __restrict__ lhs_s,
                                                const float* __restrict__ rhs_s,
                                                const float* __restrict__ sa_bias,
                                                unsigned short* __restrict__ aTh,
                                                unsigned short* __restrict__ aTl) {
    __shared__ float L[256 * 25];
    __shared__ float R[16 * Tt_];
    __shared__ float Bt[256 * 17];
    int b = blockIdx.y, tid = threadIdx.x;
    int p0 = (blockIdx.x >> 1) * 16;
    int m0 = (blockIdx.x & 1) * 256;
    for (int i = tid; i < 256 * Tt_; i += 256) {
        int m = i / Tt_, t = i - m * Tt_;
        L[m * 25 + t] = lhs_s[b * Nn_ * Tt_ + (m0 + m) * Tt_ + t];
    }
    for (int i = tid; i < 16 * Tt_; i += 256) R[i] = rhs_s[b * Nn_ * Tt_ + p0 * Tt_ + i];
    for (int i = tid; i < 256 * 16; i += 256) {
        int m = i >> 4, j = i & 15;
        Bt[m * 17 + j] = sa_bias[(size_t)(m0 + m) * Nn_ + p0 + j];
    }
    __syncthreads();
    for (int idx = tid; idx < 16 * 256; idx += 256) {
        int r = idx >> 8, mm = idx & 255;
        const float* lp = L + mm * 25;
        const float* rp = R + r * Tt_;
        float s = 0.f;
#pragma unroll
        for (int t = 0; t < Tt_; ++t) s += lp[t] * rp[t];
        float v = sigmoidf_(s + Bt[mm * 17 + r]);
        unsigned short hi = f2bf(v);
        size_t o = ((size_t)b * Nn_ + p0 + r) * Nn_ + m0 + mm;
        aTh[o] = hi;
        aTl[o] = f2bf(v - bf2f(hi));
    }
}

__global__ void kprojsplit(const float* __restrict__ proj,
                           unsigned short* __restrict__ pBh,
                           unsigned short* __restrict__ pBl) {
    int i = blockIdx.x * 256 + threadIdx.x;
    float v = proj[i];
    unsigned short hi = f2bf(v);
    pBh[i] = hi;
    pBl[i] = f2bf(v - bf2f(hi));
}

// chebT[k][p][m] = cheb[k][m][p]
__global__ __launch_bounds__(256) void kchebT(const float* __restrict__ cheb,
                                              float* __restrict__ chebT) {
    __shared__ float tl[64][65];
    int p0 = blockIdx.x * 64, m0 = blockIdx.y * 64, k = blockIdx.z;
    int tid = threadIdx.x, j = tid & 63, i4 = tid >> 6;
#pragma unroll
    for (int r = 0; r < 16; ++r) {
        int i = i4 + r * 4;
        tl[i][j] = cheb[(size_t)k * Nn_ * Nn_ + (size_t)(m0 + i) * Nn_ + p0 + j];
    }
    __syncthreads();
#pragma unroll
    for (int r = 0; r < 16; ++r) {
        int pp = i4 + r * 4;
        chebT[(size_t)k * Nn_ * Nn_ + (size_t)(p0 + pp) * Nn_ + m0 + j] = tl[j][pp];
    }
}

// ST[b][p][n] = sum_m attnT[b][p][m] * proj[n][m]  via split-bf16 MFMA
// XCD-swizzled: 512 blocks = 8 XCDs x 64.
__global__ __launch_bounds__(256) void ksgemm_mfma(const unsigned short* __restrict__ aTh,
                                                   const unsigned short* __restrict__ aTl,
                                                   const unsigned short* __restrict__ pBh,
                                                   const unsigned short* __restrict__ pBl,
                                                   float* __restrict__ ST) {
    __shared__ unsigned short Ah[512 * 8], Al[512 * 8], Bh[512 * 8], Bl[512 * 8];
    int lin = blockIdx.x + 4 * (blockIdx.y + 4 * blockIdx.z);   // 0..511
    lin = (lin & 7) * 64 + (lin >> 3);                          // bijective (512%8==0)
    int nt = lin & 3;
    int pt = (lin >> 2) & 3;
    int b = lin >> 4;
    int p0 = pt * 128, n0 = nt * 128;
    int tid = threadIdx.x, wid = tid >> 6, lane = tid & 63;
    int l15 = lane & 15, l4 = lane >> 4;
    int wm = (wid & 1) * 64, wn = (wid >> 1) * 64;
    const unsigned short* Abh = aTh + (size_t)b * Nn_ * Nn_;
    const unsigned short* Abl = aTl + (size_t)b * Nn_ * Nn_;

    int cp0 = wid * 128 + lane, cp1 = cp0 + 64;
    int r0 = cp0 >> 2, k0c = (cp0 & 3) ^ ((r0 >> 1) & 3);
    int r1 = cp1 >> 2, k1c = (cp1 & 3) ^ ((r1 >> 1) & 3);
    const unsigned short* gAh0 = Abh + (size_t)(p0 + r0) * Nn_ + k0c * 8;
    const unsigned short* gAh1 = Abh + (size_t)(p0 + r1) * Nn_ + k1c * 8;
    const unsigned short* gAl0 = Abl + (size_t)(p0 + r0) * Nn_ + k0c * 8;
    const unsigned short* gAl1 = Abl + (size_t)(p0 + r1) * Nn_ + k1c * 8;
    const unsigned short* gBh0 = pBh + (size_t)(n0 + r0) * Nn_ + k0c * 8;
    const unsigned short* gBh1 = pBh + (size_t)(n0 + r1) * Nn_ + k1c * 8;
    const unsigned short* gBl0 = pBl + (size_t)(n0 + r0) * Nn_ + k0c * 8;
    const unsigned short* gBl1 = pBl + (size_t)(n0 + r1) * Nn_ + k1c * 8;
    unsigned short* lAh0 = Ah + (size_t)cp0 * 8;
    unsigned short* lAh1 = Ah + (size_t)cp1 * 8;
    unsigned short* lAl0 = Al + (size_t)cp0 * 8;
    unsigned short* lAl1 = Al + (size_t)cp1 * 8;
    unsigned short* lBh0 = Bh + (size_t)cp0 * 8;
    unsigned short* lBh1 = Bh + (size_t)cp1 * 8;
    unsigned short* lBl0 = Bl + (size_t)cp0 * 8;
    unsigned short* lBl1 = Bl + (size_t)cp1 * 8;

    int ca[4], cb[4];
#pragma unroll
    for (int i = 0; i < 4; ++i) {
        int row = wm + i * 16 + l15;
        ca[i] = row * 4 + (l4 ^ ((row >> 1) & 3));
        row = wn + i * 16 + l15;
        cb[i] = row * 4 + (l4 ^ ((row >> 1) & 3));
    }

    f32x4 acc[4][4];
#pragma unroll
    for (int i = 0; i < 4; ++i)
#pragma unroll
        for (int j = 0; j < 4; ++j) acc[i][j] = (f32x4){0.f, 0.f, 0.f, 0.f};

    for (int ks = 0; ks < 16; ++ks) {
        __syncthreads();
        async16(gAh0 + ks * 32, lAh0);
        async16(gAh1 + ks * 32, lAh1);
        async16(gAl0 + ks * 32, lAl0);
        async16(gAl1 + ks * 32, lAl1);
        async16(gBh0 + ks * 32, lBh0);
        async16(gBh1 + ks * 32, lBh1);
        async16(gBl0 + ks * 32, lBl0);
        async16(gBl1 + ks * 32, lBl1);
        __syncthreads();
        bf16x8 ah[4], al[4], bh[4], bl[4];
#pragma unroll
        for (int i = 0; i < 4; ++i) {
            ah[i] = *(const bf16x8*)(Ah + (size_t)ca[i] * 8);
            al[i] = *(const bf16x8*)(Al + (size_t)ca[i] * 8);
        }
#pragma unroll
        for (int j = 0; j < 4; ++j) {
            bh[j] = *(const bf16x8*)(Bh + (size_t)cb[j] * 8);
            bl[j] = *(const bf16x8*)(Bl + (size_t)cb[j] * 8);
        }
#pragma unroll
        for (int i = 0; i < 4; ++i)
#pragma unroll
            for (int j = 0; j < 4; ++j) {
                acc[i][j] = __builtin_amdgcn_mfma_f32_16x16x32_bf16(ah[i], bh[j], acc[i][j], 0, 0, 0);
                acc[i][j] = __builtin_amdgcn_mfma_f32_16x16x32_bf16(ah[i], bl[j], acc[i][j], 0, 0, 0);
                acc[i][j] = __builtin_amdgcn_mfma_f32_16x16x32_bf16(al[i], bh[j], acc[i][j], 0, 0, 0);
            }
    }

    float* Cb = ST + (size_t)b * Nn_ * Nn_;
#pragma unroll
    for (int i = 0; i < 4; ++i)
#pragma unroll
        for (int j = 0; j < 4; ++j) {
            int p = p0 + wm + i * 16 + l4 * 4;
            int n = n0 + wn + j * 16 + l15;
#pragma unroll
            for (int r = 0; r < 4; ++r)
                Cb[(size_t)(p + r) * Nn_ + n] = acc[i][j][r];
        }
}

// fused row-softmax + cheb multiply + bf16 AT write (one wave per ST row)
__global__ __launch_bounds__(256) void kjaT(const float* __restrict__ ST,
                                            const float* __restrict__ chebT,
                                            unsigned short* __restrict__ AT) {
    int row = blockIdx.x * 4 + (threadIdx.x >> 6);   // b*512 + p
    int lane = threadIdx.x & 63;
    const float* rp = ST + (size_t)row * Nn_ + lane * 8;
    float4 a = *(const float4*)rp;
    float4 c = *(const float4*)(rp + 4);
    float m = fmaxf(fmaxf(fmaxf(a.x, a.y), fmaxf(a.z, a.w)),
                    fmaxf(fmaxf(c.x, c.y), fmaxf(c.z, c.w)));
#pragma unroll
    for (int off = 32; off > 0; off >>= 1) m = fmaxf(m, __shfl_xor(m, off, 64));
    float e[8];
    e[0] = __expf(a.x - m); e[1] = __expf(a.y - m); e[2] = __expf(a.z - m); e[3] = __expf(a.w - m);
    e[4] = __expf(c.x - m); e[5] = __expf(c.y - m); e[6] = __expf(c.z - m); e[7] = __expf(c.w - m);
    float s = e[0] + e[1] + e[2] + e[3] + e[4] + e[5] + e[6] + e[7];
#pragma unroll
    for (int off = 32; off > 0; off >>= 1) s += __shfl_xor(s, off, 64);
    float inv = 1.0f / s;
#pragma unroll
    for (int i = 0; i < 8; ++i) e[i] *= inv;
    int b = row >> 9, p = row & 511;
#pragma unroll
    for (int k = 0; k < 3; ++k) {
        const float* cp = chebT + (size_t)k * 262144 + (size_t)p * Nn_ + lane * 8;
        float4 c0 = *(const float4*)cp;
        float4 c1 = *(const float4*)(cp + 4);
        u16x4 o0, o1;
        o0[0] = f2bf(c0.x * e[0]); o0[1] = f2bf(c0.y * e[1]);
        o0[2] = f2bf(c0.z * e[2]); o0[3] = f2bf(c0.w * e[3]);
        o1[0] = f2bf(c1.x * e[4]); o1[1] = f2bf(c1.y * e[5]);
        o1[2] = f2bf(c1.z * e[6]); o1[3] = f2bf(c1.w * e[7]);
        unsigned short* op = AT + (size_t)k * 8388608 + (size_t)b * 262144 + (size_t)p * Nn_ + lane * 8;
        *(u16x4*)op = o0;
        *(u16x4*)(op + 4) = o1;
    }
}

// XT[b][q][m] bf16 = x[b][m][q]
__global__ __launch_bounds__(256) void kxT(const float* __restrict__ x,
                                           unsigned short* __restrict__ XT) {
    __shared__ float tl[64][65];
    int q0 = blockIdx.x * 64, m0 = blockIdx.y * 64, b = blockIdx.z;
    int tid = threadIdx.x, j = tid & 63, i4 = tid >> 6;
#pragma unroll
    for (int r = 0; r < 16; ++r) {
        int i = i4 + r * 4;
        tl[i][j] = x[((size_t)(b * Nn_ + m0 + i)) * 768 + q0 + j];
    }
    __syncthreads();
#pragma unroll
    for (int r = 0; r < 16; ++r) {
        int qq = i4 + r * 4;
        XT[((size_t)b * 768 + q0 + qq) * Nn_ + m0 + j] = f2bf(tl[j][qq]);
    }
}

// H[b][p][q] bf16 = sum_m AT_k[b][p][m] * XT[b][q][m]; grid.z = k*32+b (3 k fused)
// XCD-swizzled: 2304 blocks = 8 XCDs x 288.
__global__ __launch_bounds__(256) void hgemm_mfma(const unsigned short* __restrict__ AT,
                                                  const unsigned short* __restrict__ XT,
                                                  unsigned short* __restrict__ H) {
    __shared__ unsigned short As[512 * 8];
    __shared__ unsigned short Bs[512 * 8];
    int lin = blockIdx.x + 6 * (blockIdx.y + 4 * blockIdx.z);   // 0..2303
    lin = (lin & 7) * 288 + (lin >> 3);                         // bijective (2304%8==0)
    int qt = lin % 6;
    int rem = lin / 6;
    int pt = rem & 3;
    int bz = rem >> 2;
    int b = bz & 31, kk2 = bz >> 5;
    int p0 = pt * 128;
    int q0 = qt * 128;
    int tid = threadIdx.x;
    int wid = tid >> 6, lane = tid & 63;
    int l15 = lane & 15, l4 = lane >> 4;
    int wm = (wid & 1) * 64, wn = (wid >> 1) * 64;
    const unsigned short* Ab = AT + (size_t)kk2 * 8388608 + (size_t)b * Nn_ * Nn_;
    const unsigned short* Bb = XT + (size_t)b * 768 * Nn_;

    int cp0 = wid * 128 + lane;
    int cp1 = cp0 + 64;
    int rA0 = cp0 >> 2, kA0 = (cp0 & 3) ^ ((rA0 >> 1) & 3);
    int rA1 = cp1 >> 2, kA1 = (cp1 & 3) ^ ((rA1 >> 1) & 3);
    const unsigned short* gA0 = Ab + (size_t)(p0 + rA0) * Nn_ + kA0 * 8;
    const unsigned short* gA1 = Ab + (size_t)(p0 + rA1) * Nn_ + kA1 * 8;
    const unsigned short* gB0 = Bb + (size_t)(q0 + rA0) * Nn_ + kA0 * 8;
    const unsigned short* gB1 = Bb + (size_t)(q0 + rA1) * Nn_ + kA1 * 8;
    unsigned short* lA0 = As + (size_t)(wid * 128) * 8;
    unsigned short* lA1 = As + (size_t)(wid * 128 + 64) * 8;
    unsigned short* lB0 = Bs + (size_t)(wid * 128) * 8;
    unsigned short* lB1 = Bs + (size_t)(wid * 128 + 64) * 8;

    int ca[4], cb[4];
#pragma unroll
    for (int i = 0; i < 4; ++i) {
        int row = wm + i * 16 + l15;
        ca[i] = row * 4 + (l4 ^ ((row >> 1) & 3));
        row = wn + i * 16 + l15;
        cb[i] = row * 4 + (l4 ^ ((row >> 1) & 3));
    }

    f32x4 acc[4][4];
#pragma unroll
    for (int i = 0; i < 4; ++i)
#pragma unroll
        for (int j = 0; j < 4; ++j) acc[i][j] = (f32x4){0.f, 0.f, 0.f, 0.f};

    for (int ks = 0; ks < 16; ++ks) {
        __syncthreads();
        async16(gA0 + ks * 32, lA0);
        async16(gA1 + ks * 32, lA1);
        async16(gB0 + ks * 32, lB0);
        async16(gB1 + ks * 32, lB1);
        __syncthreads();
        bf16x8 af[4], bfv[4];
#pragma unroll
        for (int i = 0; i < 4; ++i) af[i] = *(const bf16x8*)(As + (size_t)ca[i] * 8);
#pragma unroll
        for (int j = 0; j < 4; ++j) bfv[j] = *(const bf16x8*)(Bs + (size_t)cb[j] * 8);
#pragma unroll
        for (int i = 0; i < 4; ++i)
#pragma unroll
            for (int j = 0; j < 4; ++j)
                acc[i][j] = __builtin_amdgcn_mfma_f32_16x16x32_bf16(af[i], bfv[j], acc[i][j], 0, 0, 0);
    }

    unsigned short* Hb = H + (size_t)kk2 * HS_ + (size_t)b * Nn_ * 768;
#pragma unroll
    for (int i = 0; i < 4; ++i)
#pragma unroll
        for (int j = 0; j < 4; ++j) {
            int p = p0 + wm + i * 16 + l4 * 4;
            int q = q0 + wn + j * 16 + l15;
#pragma unroll
            for (int r = 0; r < 4; ++r)
                Hb[(size_t)(p + r) * 768 + q] = f2bf(acc[i][j][r]);
        }
}

// prep: WA[r][kf] bf16 (kf<96: w_cheb[kf][r]; kf>=96: skip_w[r][kf-96])
//       WC[(j*64+c)][g] bf16 = time_w[c][g][j]; also zero tmp for kab atomics
__global__ void kprep(const float* __restrict__ wch, const float* __restrict__ skw,
                      const float* __restrict__ tw,
                      unsigned short* __restrict__ WA, unsigned short* __restrict__ WC,
                      float* __restrict__ tmp) {
    int tid = threadIdx.x;
    for (int i = tid; i < 64 * 128; i += 256) {
        int r = i >> 7, kf = i & 127;
        float v = (kf < 96) ? wch[kf * 64 + r] : skw[r * 32 + (kf - 96)];
        WA[i] = f2bf(v);
    }
    for (int i = tid; i < 192 * 64; i += 256) {
        int j = i / 4096, c = (i >> 6) & 63, g = i & 63;
        WC[i] = f2bf(tw[c * 192 + g * 3 + j]);
    }
    for (int i = tid; i < 24576; i += 256) tmp[i] = 0.f;
}

// Staging macros for ktail: named registers, compile-time element indexing.
#define LOADU(utg_, un_, ufg_, uk_, R0, R1, R2, R3, n0_)                                  \
    do {                                                                                  \
        int t0_ = (utg_) * 4, f0_ = (ufg_) * 4;                                           \
        if ((uk_) < 3) {                                                                  \
            const unsigned short* hp_ = H + (size_t)(uk_) * HS_ +                         \
                ((size_t)b * Nn_ + (n0_) + (un_)) * 768 + f0_ * 24 + t0_;                 \
            R0 = *(const u16x4*)hp_;                                                      \
            R1 = *(const u16x4*)(hp_ + 24);                                               \
            R2 = *(const u16x4*)(hp_ + 48);                                               \
            R3 = *(const u16x4*)(hp_ + 72);                                               \
        } else {                                                                          \
            const float* xp_ = x + ((size_t)b * Nn_ + (n0_) + (un_)) * 768 + f0_ * 24 + t0_; \
            float4 v0_ = *(const float4*)xp_;                                             \
            float4 v1_ = *(const float4*)(xp_ + 24);                                      \
            float4 v2_ = *(const float4*)(xp_ + 48);                                      \
            float4 v3_ = *(const float4*)(xp_ + 72);                                      \
            R0 = (u16x4){f2bf(v0_.x), f2bf(v0_.y), f2bf(v0_.z), f2bf(v0_.w)};             \
            R1 = (u16x4){f2bf(v1_.x), f2bf(v1_.y), f2bf(v1_.z), f2bf(v1_.w)};             \
            R2 = (u16x4){f2bf(v2_.x), f2bf(v2_.y), f2bf(v2_.z), f2bf(v2_.w)};             \
            R3 = (u16x4){f2bf(v3_.x), f2bf(v3_.y), f2bf(v3_.z), f2bf(v3_.w)};             \
        }                                                                                 \
    } while (0)

#define WRITEU(utg_, un_, ufg_, uk_, R0, R1, R2, R3)                                      \
    do {                                                                                  \
        int t0_ = (utg_) * 4;                                                             \
        int kc4_ = (uk_) * 4 + ((ufg_) >> 1);                                             \
        int half_ = (ufg_) & 1;                                                           \
        int c0_ = (un_) * 24 + t0_;                                                       \
        int p0_ = (c0_ + 0) * 16 + (kc4_ ^ (((c0_ + 0) ^ ((c0_ + 0) >> 2)) & 7));         \
        int p1_ = (c0_ + 1) * 16 + (kc4_ ^ (((c0_ + 1) ^ ((c0_ + 1) >> 2)) & 7));         \
        int p2_ = (c0_ + 2) * 16 + (kc4_ ^ (((c0_ + 2) ^ ((c0_ + 2) >> 2)) & 7));         \
        int p3_ = (c0_ + 3) * 16 + (kc4_ ^ (((c0_ + 3) ^ ((c0_ + 3) >> 2)) & 7));         \
        *(u16x4*)(Hl + p0_ * 8 + half_ * 4) = (u16x4){R0[0], R1[0], R2[0], R3[0]};        \
        *(u16x4*)(Hl + p1_ * 8 + half_ * 4) = (u16x4){R0[1], R1[1], R2[1], R3[1]};        \
        *(u16x4*)(Hl + p2_ * 8 + half_ * 4) = (u16x4){R0[2], R1[2], R2[2], R3[2]};        \
        *(u16x4*)(Hl + p3_ * 8 + half_ * 4) = (u16x4){R0[3], R1[3], R2[3], R3[3]};        \
    } while (0)

#define REGLOAD(n0_)                                         \
    do {                                                     \
        LOADU(utg0, un0, ufg0, uk0, rA0, rA1, rA2, rA3, n0_);\
        LOADU(utg1, un1, ufg1, uk1, rB0, rB1, rB2, rB3, n0_);\
        LOADU(utg2, un2, ufg2, uk2, rC0, rC1, rC2, rC3, n0_);\
    } while (0)

#define HLWRITE()                                            \
    do {                                                     \
        WRITEU(utg0, un0, ufg0, uk0, rA0, rA1, rA2, rA3);    \
        WRITEU(utg1, un1, ufg1, uk1, rB0, rB1, rB2, rB3);    \
        WRITEU(utg2, un2, ufg2, uk2, rC0, rC1, rC2, rC3);    \
    } while (0)

// -------- fused tail, 4-tile persistent blocks. NO min-occupancy bound:
// R9/R10's __launch_bounds__(256,4) capped the allocator at 64 VGPR and
// spilled ~150MB/dir to scratch (FETCH 267MB, WRITE 251MB). This kernel
// needs ~150 VGPRs; LDS (39.4KB) caps residency anyway, so an unbounded
// allocation costs at most 4->3 blocks/CU (proven insensitive in R5/R7). --
__global__ __launch_bounds__(256) void ktail(const unsigned short* __restrict__ H,
                                             const float* __restrict__ x,
                                             const unsigned short* __restrict__ WA,
                                             const unsigned short* __restrict__ WC,
                                             const float* __restrict__ time_b,
                                             const float* __restrict__ skip_b,
                                             const float* __restrict__ ln_g,
                                             const float* __restrict__ ln_b,
                                             float* __restrict__ out) {
    __shared__ __align__(16) unsigned short Hl[96 * 16 * 8];   // 96 cols x 16 chunks x 8 shorts
    __shared__ __align__(16) unsigned short Gl[104 * 64];      // 104 rows x 8 chunks x 8 shorts
    __shared__ float biasS[64], lgS[64], lbS[64];
    __shared__ float muS[96], rsS[96];

    int b = blockIdx.y;
    int nb = blockIdx.x * 16;          // 4 tiles: n0 = nb + tc*4
    int tid = threadIdx.x;
    int w = tid >> 6, lane = tid & 63, l15 = lane & 15, l4 = lane >> 4;

    // weight fragments (once per block, amortized over 4 tiles)
    bf16x8 af[4], cf[3][2];
#pragma unroll
    for (int q = 0; q < 4; ++q)
        af[q] = *(const bf16x8*)(WA + (size_t)(16 * w + l15) * 128 + q * 32 + l4 * 8);
#pragma unroll
    for (int j = 0; j < 3; ++j)
#pragma unroll
        for (int kc = 0; kc < 2; ++kc)
            cf[j][kc] = *(const bf16x8*)(WC + (size_t)(j * 64 + 16 * w + l15) * 64 + kc * 32 + l4 * 8);

    // per-thread staging-unit decode (tile-invariant): u = (((k*8+fg)*4+n)*6+tg)
    int u0 = tid, u1 = 256 + tid, u2 = 512 + tid;
    int utg0 = u0 % 6, un0 = (u0 / 6) & 3, ufg0 = (u0 / 24) & 7, uk0 = u0 / 192;
    int utg1 = u1 % 6, un1 = (u1 / 6) & 3, ufg1 = (u1 / 24) & 7, uk1 = u1 / 192;
    int utg2 = u2 % 6, un2 = (u2 / 6) & 3, ufg2 = (u2 / 24) & 7, uk2 = u2 / 192;

    u16x4 rA0, rA1, rA2, rA3, rB0, rB1, rB2, rB3, rC0, rC1, rC2, rC3;

    // prologue: tile 0 staged; borders + params
    REGLOAD(nb);
    if (tid < 64) {
        int n = tid >> 4, rr = (tid >> 3) & 1, gc = tid & 7;
        int row = n * 26 + rr * 25;
        int posg = row * 8 + (gc ^ (row & 7));
        *(float4*)(void*)(Gl + posg * 8) = make_float4(0.f, 0.f, 0.f, 0.f);
        biasS[tid] = time_b[tid] + skip_b[tid];
        lgS[tid] = ln_g[tid];
        lbS[tid] = ln_b[tid];
    }
    HLWRITE();
    __syncthreads();
    REGLOAD(nb + 4);   // tile 1 in flight during tile 0 stage1

#pragma unroll
    for (int tc = 0; tc < 4; ++tc) {
        int n0 = nb + tc * 4;

        // stage 1: gcn (K=96) + skip (K=32), relu(gcn) -> Gl bf16
        f32x4 accs[6];
#pragma unroll
        for (int ct = 0; ct < 6; ++ct) {
            int col = ct * 16 + l15;
            int cx = (col ^ (col >> 2)) & 7;
            bf16x8 h0 = *(const bf16x8*)(Hl + (col * 16 + ((0 + l4) ^ cx)) * 8);
            bf16x8 h1 = *(const bf16x8*)(Hl + (col * 16 + ((4 + l4) ^ cx)) * 8);
            bf16x8 h2 = *(const bf16x8*)(Hl + (col * 16 + ((8 + l4) ^ cx)) * 8);
            bf16x8 h3 = *(const bf16x8*)(Hl + (col * 16 + ((12 + l4) ^ cx)) * 8);
            f32x4 g = (f32x4){0.f, 0.f, 0.f, 0.f};
            g = __builtin_amdgcn_mfma_f32_16x16x32_bf16(af[0], h0, g, 0, 0, 0);
            g = __builtin_amdgcn_mfma_f32_16x16x32_bf16(af[1], h1, g, 0, 0, 0);
            g = __builtin_amdgcn_mfma_f32_16x16x32_bf16(af[2], h2, g, 0, 0, 0);
            f32x4 s = (f32x4){0.f, 0.f, 0.f, 0.f};
            s = __builtin_amdgcn_mfma_f32_16x16x32_bf16(af[3], h3, s, 0, 0, 0);
            accs[ct] = s;
            int n = col / 24, t = col - n * 24;
            int row = n * 26 + t + 1;
            int gc = 2 * w + (l4 >> 1);
            int posg = row * 8 + (gc ^ (row & 7));
            u16x4 pk;
#pragma unroll
            for (int r = 0; r < 4; ++r) pk[r] = f2bf(g[r] > 0.f ? g[r] : 0.f);
            *(u16x4*)(Gl + posg * 8 + (l4 & 1) * 4) = pk;
        }
        __syncthreads();   // B: Hl reads + Gl writes complete

        // write next tile's staged regs into Hl; refill regs with tile tc+2
        if (tc < 3) {
            HLWRITE();
            if (tc < 2) REGLOAD(nb + (tc + 2) * 4);
        }

        // stage 2: conv as 3 shifted GEMMs (K=64) + skip + bias + relu -> regs
        f32x4 oo[6];
        float ps6[6], pq6[6];
#pragma unroll
        for (int ct = 0; ct < 6; ++ct) {
            int col = ct * 16 + l15;
            int n = col / 24, t = col - n * 24;
            f32x4 acc = accs[ct];
#pragma unroll
            for (int j = 0; j < 3; ++j) {
                int row = n * 26 + t + j;
                int rx = row & 7;
                bf16x8 g0 = *(const bf16x8*)(Gl + (row * 8 + (l4 ^ rx)) * 8);
                bf16x8 g1 = *(const bf16x8*)(Gl + (row * 8 + ((l4 + 4) ^ rx)) * 8);
                acc = __builtin_amdgcn_mfma_f32_16x16x32_bf16(cf[j][0], g0, acc, 0, 0, 0);
                acc = __builtin_amdgcn_mfma_f32_16x16x32_bf16(cf[j][1], g1, acc, 0, 0, 0);
            }
            int cb = 16 * w + 4 * l4;
            f32x4 bv = *(const f32x4*)(biasS + cb);
            f32x4 o;
#pragma unroll
            for (int r = 0; r < 4; ++r) {
                float v = acc[r] + bv[r];
                o[r] = v > 0.f ? v : 0.f;
            }
            oo[ct] = o;
            float ps = o[0] + o[1] + o[2] + o[3];
            float pq = o[0] * o[0] + o[1] * o[1] + o[2] * o[2] + o[3] * o[3];
            ps += __shfl_xor(ps, 16, 64);
            ps += __shfl_xor(ps, 32, 64);
            pq += __shfl_xor(pq, 16, 64);
            pq += __shfl_xor(pq, 32, 64);
            ps6[ct] = ps;
            pq6[ct] = pq;
        }
        __syncthreads();   // C: Gl reads done -> rows 0..23 reusable as LN scratch

        float* lnP = (float*)Gl;   // [0..383] sums, [384..767] sq-sums (w*96+col)
        if (l4 == 0) {
#pragma unroll
            for (int ct = 0; ct < 6; ++ct) {
                int col = ct * 16 + l15;
                lnP[w * 96 + col] = ps6[ct];
                lnP[384 + w * 96 + col] = pq6[ct];
            }
        }
        __syncthreads();   // D
        if (tid < 96) {
            float s = lnP[tid] + lnP[96 + tid] + lnP[192 + tid] + lnP[288 + tid];
            float q = lnP[384 + tid] + lnP[480 + tid] + lnP[576 + tid] + lnP[672 + tid];
            float mu = s * (1.0f / 64.0f);
            float var = q * (1.0f / 64.0f) - mu * mu;
            muS[tid] = mu;
            rsS[tid] = rsqrtf(var + 1e-5f);
        }
        __syncthreads();   // E

        // direct register store: out[((b*N+n)*64+c)*24+t], c = 16w+4*l4+r
        float* ob = out + ((size_t)b * Nn_ + n0) * (TC_ * Tt_);
        int cb = 16 * w + 4 * l4;
        f32x4 lgv = *(const f32x4*)(lgS + cb);
        f32x4 lbv = *(const f32x4*)(lbS + cb);
#pragma unroll
        for (int ct = 0; ct < 6; ++ct) {
            int col = ct * 16 + l15;
            int n = col / 24, t = col - n * 24;
            float mu = muS[col], rs = rsS[col];
            f32x4 o = oo[ct];
            float* op = ob + (size_t)(n * 64 + cb) * 24 + t;
#pragma unroll
            for (int r = 0; r < 4; ++r)
                op[r * 24] = (o[r] - mu) * rs * lgv[r] + lbv[r];
        }
        // re-zero Gl row 0 (border clobbered by lnP); protected by next barrier B
        if (tc < 3 && tid < 8)
            *(float4*)(void*)(Gl + tid * 8) = make_float4(0.f, 0.f, 0.f, 0.f);
    }
}

extern "C" void kernel_launch(void* const* d_in, const int* in_sizes, int n_in,
                              void* d_out, int out_size, void* d_ws, size_t ws_size,
                              hipStream_t stream) {
    const float* x       = (const float*)d_in[0];
    const float* cheb    = (const float*)d_in[1];
    const float* w_cheb  = (const float*)d_in[2];
    const float* sa_wa   = (const float*)d_in[3];
    const float* sa_wb   = (const float*)d_in[4];
    const float* sa_wc   = (const float*)d_in[5];
    const float* sa_bias = (const float*)d_in[6];
    const float* sa_proj = (const float*)d_in[7];
    const float* ta_w1   = (const float*)d_in[8];
    const float* ta_w2   = (const float*)d_in[9];
    const float* ta_w3   = (const float*)d_in[10];
    const float* ta_bias = (const float*)d_in[11];
    const float* ta_proj = (const float*)d_in[12];
    const float* time_w  = (const float*)d_in[13];
    const float* time_b  = (const float*)d_in[14];
    const float* skip_w  = (const float*)d_in[15];
    const float* skip_b  = (const float*)d_in[16];
    const float* ln_g    = (const float*)d_in[17];
    const float* ln_b    = (const float*)d_in[18];
    float* out = (float*)d_out;

    // ---- workspace layout (~195 MB) ----
    float* cur   = (float*)d_ws;
    float* tmp   = cur;            cur += 24576;
    float* lhs_t = cur;            cur += 393216;
    float* rhs_t = cur;            cur += 393216;
    float* tw    = cur;            cur += 18432;
    float* lhs_s = cur;            cur += 393216;
    float* rhs_s = cur;            cur += 393216;
    unsigned short* WAbuf = (unsigned short*)cur;            // 8192 us
    unsigned short* WCbuf = WAbuf + 8192;                    // 12288 us
    cur += 10240;
    unsigned short* pBh = (unsigned short*)cur;              // 262144 us
    unsigned short* pBl = pBh + 262144;                      // 262144 us
    cur += 262144;
    float* chebT = cur;            cur += 786432;
    unsigned short* regionA = (unsigned short*)cur;          // attnT hi/lo, then AT x3
    unsigned short* aTh = regionA;
    unsigned short* aTl = regionA + 8388608;
    unsigned short* ATb = regionA;
    cur += 12582912;
    float* STbuf = cur;            cur += 8388608;
    unsigned short* XT = (unsigned short*)cur;               // 12582912 us
    cur += 6291456;
    unsigned short* hbuf = (unsigned short*)cur;             // 37748736 us

    kprep<<<1, 256, 0, stream>>>(w_cheb, skip_w, time_w, WAbuf, WCbuf, tmp);
    kprojsplit<<<1024, 256, 0, stream>>>(sa_proj, pBh, pBl);
    kchebT<<<dim3(8, 8, 3), 256, 0, stream>>>(cheb, chebT);
    kxT<<<dim3(12, 8, 32), 256, 0, stream>>>(x, XT);
    kab<<<dim3(16, 32), 256, 0, stream>>>(x, ta_w1, ta_w3, tmp, rhs_t);
    kc_lhs<<<1536, 256, 0, stream>>>(tmp, ta_w2, lhs_t);
    kd_temporal<<<32, 576, 0, stream>>>(lhs_t, rhs_t, ta_bias, ta_proj, tw);
    ke_spatial<<<dim3(512, 32), 256, 0, stream>>>(x, tw, sa_wa, sa_wb, sa_wc, lhs_s, rhs_s);
    kg_attnT<<<dim3(64, 32), 256, 0, stream>>>(lhs_s, rhs_s, sa_bias, aTh, aTl);
    ksgemm_mfma<<<dim3(4, 4, 32), 256, 0, stream>>>(aTh, aTl, pBh, pBl, STbuf);
    kjaT<<<4096, 256, 0, stream>>>(STbuf, chebT, ATb);
    hgemm_mfma<<<dim3(6, 4, 96), 256, 0, stream>>>(ATb, XT, hbuf);
    ktail<<<dim3(32, 32), 256, 0, stream>>>(hbuf, x, WAbuf, WCbuf,
                                            time_b, skip_b, ln_g, ln_b, out);
}